// Round 9
// baseline (805.850 us; speedup 1.0000x reference)
//
#include <hip/hip_runtime.h>
#include <math.h>

#define N_NODES 50000
#define N_EDGES 1600000
#define D_IN 128
#define D_HID 128
#define D_OUT 64
#define N_EXPERT 16
#define NB 8     // nodes per block in last kernel
#define GNB 128  // nodes per chunk in expert GEMM (W traffic amortized 2x)
#define NYB 256  // chunk-slots per expert (stride loop handles any skew)
#define NBG 16   // nodes per block in gate kernel (50000 % 16 == 0)
#define NGBLK (N_NODES / NBG)   // 3125 gate blocks per layer
#define XR4 33   // padded x-chunk row stride in float4 (132 floats)

// ---------------- gate: logits + softmax-std + argmax ------------------------
// One block = 256 threads = NBG(16) nodes. Thread (e = t&15, j = t>>4).
// Wg staged TRANSPOSED in LDS (wgt[e][d], +4 pad); x staged via float4.
__global__ __launch_bounds__(256) void gate_kernel(
    const float* __restrict__ x, const float* __restrict__ Wg, const float* __restrict__ bg,
    int* __restrict__ eidx, float* __restrict__ gpart)
{
    __shared__ float xs[NBG][132];           // +4 pad: bank rotation per row
    __shared__ float wgt[N_EXPERT][132];     // transposed gate weights, +4 pad
    __shared__ float sred[NBG];
    const int n0 = blockIdx.x * NBG;
    const int t = threadIdx.x;

    // Wg: 512 float4 coalesced reads -> transposed scalar LDS stores (2/thread)
    {
        const float4* __restrict__ Wg4 = (const float4*)Wg;
        float4 v = Wg4[t];
        int d = t >> 2, e4 = (t & 3) * 4;
        wgt[e4 + 0][d] = v.x; wgt[e4 + 1][d] = v.y; wgt[e4 + 2][d] = v.z; wgt[e4 + 3][d] = v.w;
        v = Wg4[t + 256];
        d += 64;
        wgt[e4 + 0][d] = v.x; wgt[e4 + 1][d] = v.y; wgt[e4 + 2][d] = v.z; wgt[e4 + 3][d] = v.w;
    }
    // x: 16 rows * 32 float4 = 512 float4 (2/thread), coalesced
    {
        int id = t, row = id >> 5, c4 = id & 31;
        *(float4*)&xs[row][4 * c4] = ((const float4*)(x + (size_t)(n0 + row) * 128))[c4];
        id = t + 256; row = id >> 5; c4 = id & 31;
        *(float4*)&xs[row][4 * c4] = ((const float4*)(x + (size_t)(n0 + row) * 128))[c4];
    }
    __syncthreads();

    const int e = t & 15, j = t >> 4;
    float lg = bg[e];
    #pragma unroll
    for (int d4 = 0; d4 < 32; ++d4) {        // d-ascending FMA order preserved
        const float4 xv = *(const float4*)&xs[j][4 * d4];
        const float4 wv = *(const float4*)&wgt[e][4 * d4];
        lg = fmaf(xv.x, wv.x, lg);
        lg = fmaf(xv.y, wv.y, lg);
        lg = fmaf(xv.z, wv.z, lg);
        lg = fmaf(xv.w, wv.w, lg);
    }

    // 16-lane-group reductions (lanes of one node are contiguous)
    float mx = lg;
    #pragma unroll
    for (int m = 8; m >= 1; m >>= 1) mx = fmaxf(mx, __shfl_xor(mx, m, 16));
    const float ex = expf(lg - mx);
    float se = ex;
    #pragma unroll
    for (int m = 8; m >= 1; m >>= 1) se += __shfl_xor(se, m, 16);
    const float p = ex / se;
    const float dm = p - (1.f / 16.f);
    float var = dm * dm;
    #pragma unroll
    for (int m = 8; m >= 1; m >>= 1) var += __shfl_xor(var, m, 16);

    // argmax over logits (== argmax over softmax), first-index on ties
    float bv = lg; int bi = e;
    #pragma unroll
    for (int m = 8; m >= 1; m >>= 1) {
        const float ov = __shfl_xor(bv, m, 16);
        const int oi = __shfl_xor(bi, m, 16);
        if (ov > bv || (ov == bv && oi < bi)) { bv = ov; bi = oi; }
    }
    if (e == 0) {
        eidx[n0 + j] = bi;
        sred[j] = sqrtf(var * (1.f / 15.f));
    }
    __syncthreads();
    if (t == 0) {
        float s = 0.f;
        #pragma unroll
        for (int jj = 0; jj < NBG; ++jj) s += sred[jj];
        gpart[blockIdx.x] = s;
    }
}

// ---------------- expert bucketing: hist16 -> scan16 -> scatter16 ------------
__global__ __launch_bounds__(256) void hist16_kernel(
    const int* __restrict__ eidx, int* __restrict__ ecnt)
{
    __shared__ int lcnt[N_EXPERT];
    const int t = threadIdx.x;
    const int n = blockIdx.x * 256 + t;
    if (t < N_EXPERT) lcnt[t] = 0;
    __syncthreads();
    if (n < N_NODES) atomicAdd(&lcnt[eidx[n]], 1);
    __syncthreads();
    if (t < N_EXPERT && lcnt[t] > 0) atomicAdd(&ecnt[t], lcnt[t]);
}

__global__ void scan16_kernel(const int* __restrict__ ecnt,
                              int* __restrict__ eoff, int* __restrict__ ecur)
{
    if (threadIdx.x == 0) {
        int s = 0;
        #pragma unroll
        for (int e = 0; e < N_EXPERT; ++e) { eoff[e] = s; ecur[e] = s; s += ecnt[e]; }
        eoff[N_EXPERT] = s;
    }
}

__global__ __launch_bounds__(256) void scatter16_kernel(
    const int* __restrict__ eidx, int* __restrict__ ecur, int* __restrict__ elist)
{
    __shared__ int lcnt[N_EXPERT];
    __shared__ int lbase[N_EXPERT];
    const int t = threadIdx.x;
    const int n = blockIdx.x * 256 + t;
    if (t < N_EXPERT) lcnt[t] = 0;
    __syncthreads();
    int e = 0, lpos = 0;
    if (n < N_NODES) { e = eidx[n]; lpos = atomicAdd(&lcnt[e], 1); }
    __syncthreads();
    if (t < N_EXPERT && lcnt[t] > 0) lbase[t] = atomicAdd(&ecur[t], lcnt[t]);
    __syncthreads();
    if (n < N_NODES) elist[lbase[e] + lpos] = n;
}

// ---------------- per-expert GEMM: y[n] = x[n] @ We[e] + be[e] ---------------
// grid = (16 experts, NYB=256 chunk-slots) + chunk-stride loop (handles the
// layer-2 gating collapse onto few experts).
// GNB=128 nodes/chunk: every wave still streams the full 64 KB We[e] once per
// chunk through L1/L2, but it now serves 2x nodes (W-restream was R6's bound).
// Thread tile: dg = t&31 -> dims 4dg..4dg+3, ng = t>>5 -> nodes 16ng..16ng+15.
// x chunk in LDS padded to 132 floats/row (bank rotation, no 4-way conflict).
// #pragma unroll 2 ONLY (R7 lesson: full unroll -> 256 VGPR + scratch spill).
__global__ __launch_bounds__(256, 2) void expert_gemm_kernel(
    const float* __restrict__ x, const float* __restrict__ We, const float* __restrict__ be,
    const int* __restrict__ eoff, const int* __restrict__ elist, float* __restrict__ y)
{
    __shared__ float xsd[GNB * 132];  // 66 KB padded -> 2 blocks/CU
    const int e = blockIdx.x;
    const int t = threadIdx.x;
    const int row0 = eoff[e];
    const int row1 = eoff[e + 1];

    const int dg = t & 31;   // dims 4*dg .. 4*dg+3
    const int ng = t >> 5;   // nodes 16*ng .. 16*ng+15
    const float4* __restrict__ Wv = (const float4*)(We + (size_t)e * 16384);
    const float4* __restrict__ Xv = (const float4*)xsd;
    const float4 bv = *(const float4*)&be[e * 128 + 4 * dg];

    for (int chunk = blockIdx.y;; chunk += (int)gridDim.y) {
        const int start = row0 + chunk * GNB;
        if (start >= row1) break;   // block-uniform

        // stage 128 node rows of x (float4, coalesced; dummy = first node)
        #pragma unroll
        for (int i = 0; i < 16; ++i) {
            const int id = t + 256 * i;
            const int n = id >> 5;
            const int d4 = id & 31;
            const int idx = start + n;
            const int node = elist[idx < row1 ? idx : start];
            ((float4*)xsd)[n * XR4 + d4] = ((const float4*)(x + (size_t)node * 128))[d4];
        }
        __syncthreads();

        float4 acc[16];
        #pragma unroll
        for (int k = 0; k < 16; ++k) acc[k] = bv;  // bias-init (baseline order)

        #pragma unroll 2
        for (int d4 = 0; d4 < 32; ++d4) {
            float4 w[4];   // W rows 4d4..4d4+3, this thread's 4 dims
            #pragma unroll
            for (int r = 0; r < 4; ++r) w[r] = Wv[(4 * d4 + r) * 32 + dg];
            #pragma unroll
            for (int k = 0; k < 16; ++k) {
                const float4 xv = Xv[(16 * ng + k) * XR4 + d4];
                acc[k].x = fmaf(xv.x, w[0].x, acc[k].x);
                acc[k].y = fmaf(xv.x, w[0].y, acc[k].y);
                acc[k].z = fmaf(xv.x, w[0].z, acc[k].z);
                acc[k].w = fmaf(xv.x, w[0].w, acc[k].w);
                acc[k].x = fmaf(xv.y, w[1].x, acc[k].x);
                acc[k].y = fmaf(xv.y, w[1].y, acc[k].y);
                acc[k].z = fmaf(xv.y, w[1].z, acc[k].z);
                acc[k].w = fmaf(xv.y, w[1].w, acc[k].w);
                acc[k].x = fmaf(xv.z, w[2].x, acc[k].x);
                acc[k].y = fmaf(xv.z, w[2].y, acc[k].y);
                acc[k].z = fmaf(xv.z, w[2].z, acc[k].z);
                acc[k].w = fmaf(xv.z, w[2].w, acc[k].w);
                acc[k].x = fmaf(xv.w, w[3].x, acc[k].x);
                acc[k].y = fmaf(xv.w, w[3].y, acc[k].y);
                acc[k].z = fmaf(xv.w, w[3].z, acc[k].z);
                acc[k].w = fmaf(xv.w, w[3].w, acc[k].w);
            }
        }

        #pragma unroll
        for (int k = 0; k < 16; ++k) {
            const int idx = start + 16 * ng + k;
            if (idx < row1)
                *(float4*)&y[(size_t)elist[idx] * 128 + 4 * dg] = acc[k];
        }

        __syncthreads();   // xsd fully consumed before next-chunk restage
    }
}

// ---------------- final plain linear 128 -> 64, 8 nodes/block ----------------
__global__ __launch_bounds__(64) void last_kernel(
    const float* __restrict__ h, const float* __restrict__ W, float* __restrict__ y)
{
    __shared__ float xs[NB][128];
    const int n0 = blockIdx.x * NB, t = threadIdx.x;
    #pragma unroll
    for (int j = 0; j < NB; ++j) {
        xs[j][t] = h[(size_t)(n0 + j) * 128 + t];
        xs[j][t + 64] = h[(size_t)(n0 + j) * 128 + t + 64];
    }
    __syncthreads();
    float a0 = 0.f, a1 = 0.f, a2 = 0.f, a3 = 0.f;
    float a4 = 0.f, a5 = 0.f, a6 = 0.f, a7 = 0.f;
    #pragma unroll 4
    for (int d = 0; d < 128; ++d) {
        const float w = W[d * 64 + t];
        a0 = fmaf(xs[0][d], w, a0);
        a1 = fmaf(xs[1][d], w, a1);
        a2 = fmaf(xs[2][d], w, a2);
        a3 = fmaf(xs[3][d], w, a3);
        a4 = fmaf(xs[4][d], w, a4);
        a5 = fmaf(xs[5][d], w, a5);
        a6 = fmaf(xs[6][d], w, a6);
        a7 = fmaf(xs[7][d], w, a7);
    }
    y[(size_t)(n0 + 0) * 64 + t] = a0;
    y[(size_t)(n0 + 1) * 64 + t] = a1;
    y[(size_t)(n0 + 2) * 64 + t] = a2;
    y[(size_t)(n0 + 3) * 64 + t] = a3;
    y[(size_t)(n0 + 4) * 64 + t] = a4;
    y[(size_t)(n0 + 5) * 64 + t] = a5;
    y[(size_t)(n0 + 6) * 64 + t] = a6;
    y[(size_t)(n0 + 7) * 64 + t] = a7;
}

// ---------------- CSR build: histogram -> scan -> fill -----------------------
__global__ void hist_kernel(const int* __restrict__ edst, int* __restrict__ cnt)
{
    const int i = blockIdx.x * blockDim.x + threadIdx.x;
    if (i < N_EDGES) atomicAdd(&cnt[edst[i]], 1);
}

// Single-block scan, hoisted: per-thread serial sum (49 entries) -> one
// 1024-wide Hillis-Steele -> serial write-back. cursor is a SEPARATE buffer.
__global__ __launch_bounds__(1024) void scan_kernel(
    const int* __restrict__ cnt, int* __restrict__ rowptr, int* __restrict__ cursor)
{
    __shared__ int buf[1024];
    const int t = threadIdx.x;
    const int base = t * 49;               // 49*1024 = 50176 >= N_NODES
    int s = 0;
    for (int i = 0; i < 49; ++i) {
        const int idx = base + i;
        if (idx < N_NODES) s += cnt[idx];
    }
    buf[t] = s;
    __syncthreads();
    for (int off = 1; off < 1024; off <<= 1) {
        const int add = (t >= off) ? buf[t - off] : 0;
        __syncthreads();
        buf[t] += add;
        __syncthreads();
    }
    int run = buf[t] - s;                  // exclusive prefix of this chunk
    for (int i = 0; i < 49; ++i) {
        const int idx = base + i;
        if (idx < N_NODES) {
            const int c = cnt[idx];
            rowptr[idx] = run; cursor[idx] = run;
            run += c;
        }
    }
    if (t == 1023) rowptr[N_NODES] = run;  // total edges
}

// csr_src stored as uint16 (node ids < 65536): halves the scattered-store
// footprint -> halves partial-cacheline writeback amplification (R8: 100 MB
// WRITE_SIZE for a 6.4 MB array), and halves gather's csr index reads.
__global__ void fill_kernel(const int* __restrict__ esrc, const int* __restrict__ edst,
                            int* __restrict__ cursor, unsigned short* __restrict__ csr_src)
{
    const int i = blockIdx.x * blockDim.x + threadIdx.x;
    if (i < N_EDGES) {
        const int p = atomicAdd(&cursor[edst[i]], 1);
        csr_src[p] = (unsigned short)esrc[i];
    }
}

// ---------------- gather aggregation: out[n] = bias + sum_{e in row n} h[src] -
template <int D, bool RELU>
__global__ __launch_bounds__(D) void gather_kernel(
    const float* __restrict__ h, const int* __restrict__ rowptr,
    const unsigned short* __restrict__ csr_src, const float* __restrict__ bias,
    float* __restrict__ out)
{
    const int n = blockIdx.x, t = threadIdx.x;
    const int s0 = rowptr[n], s1 = rowptr[n + 1];
    float a0 = bias[t], a1 = 0.f, a2 = 0.f, a3 = 0.f;
    int e = s0;
    for (; e + 3 < s1; e += 4) {
        const int i0 = csr_src[e + 0];
        const int i1 = csr_src[e + 1];
        const int i2 = csr_src[e + 2];
        const int i3 = csr_src[e + 3];
        a0 += h[(size_t)i0 * D + t];
        a1 += h[(size_t)i1 * D + t];
        a2 += h[(size_t)i2 * D + t];
        a3 += h[(size_t)i3 * D + t];
    }
    for (; e < s1; ++e) a0 += h[(size_t)csr_src[e] * D + t];
    float acc = (a0 + a1) + (a2 + a3);
    if (RELU) acc = fmaxf(acc, 0.f);
    out[(size_t)n * D + t] = acc;
}

// ---------------- finalize: reduce 2*NGBLK gate partials + write tail --------
__global__ __launch_bounds__(1024) void finalize_kernel(
    const float* __restrict__ gpart, float* __restrict__ out_tail)
{
    __shared__ float wsum[16];
    const int t = threadIdx.x;
    float s = 0.f;
    for (int i = t; i < 2 * NGBLK; i += 1024) s += gpart[i];
    #pragma unroll
    for (int m = 32; m >= 1; m >>= 1) s += __shfl_xor(s, m, 64);
    if ((t & 63) == 0) wsum[t >> 6] = s;
    __syncthreads();
    if (t == 0) {
        float tot = 0.f;
        #pragma unroll
        for (int w = 0; w < 16; ++w) tot += wsum[w];
        out_tail[0] = tot * (0.5f / (float)N_NODES);
        out_tail[1] = 1.0f;
    }
}

extern "C" void kernel_launch(void* const* d_in, const int* in_sizes, int n_in,
                              void* d_out, int out_size, void* d_ws, size_t ws_size,
                              hipStream_t stream)
{
    const float* x     = (const float*)d_in[0];
    const int*   edge  = (const int*)d_in[1];
    const float* Wg1   = (const float*)d_in[2];
    const float* bg1   = (const float*)d_in[3];
    const float* We1   = (const float*)d_in[4];
    const float* be1   = (const float*)d_in[5];
    const float* b1    = (const float*)d_in[6];
    const float* Wg2   = (const float*)d_in[7];
    const float* bg2   = (const float*)d_in[8];
    const float* We2   = (const float*)d_in[9];
    const float* be2   = (const float*)d_in[10];
    const float* b2    = (const float*)d_in[11];
    const float* Wlast = (const float*)d_in[12];
    const float* blast = (const float*)d_in[13];
    float* out = (float*)d_out;

    const int* esrc = edge;
    const int* edst = edge + N_EDGES;

    char* ws = (char*)d_ws;
    size_t off = 0;
    float* gpart = (float*)(ws + off); off += (size_t)2 * NGBLK * 4 + 252; off &= ~(size_t)255;
    float* A = (float*)(ws + off); off += (size_t)N_NODES * 128 * 4;
    float* B = (float*)(ws + off); off += (size_t)N_NODES * 128 * 4;
    int* rowptr = (int*)(ws + off); off += (size_t)(N_NODES + 1) * 4 + 252; off &= ~(size_t)255;
    int* cnt = (int*)(ws + off); off += (size_t)N_NODES * 4 + 252; off &= ~(size_t)255;
    int* cursor = (int*)(ws + off); off += (size_t)N_NODES * 4 + 252; off &= ~(size_t)255;
    unsigned short* csr_src = (unsigned short*)(ws + off); off += (size_t)N_EDGES * 2 + 252; off &= ~(size_t)255;
    int* elist = (int*)(ws + off); off += (size_t)N_NODES * 4 + 252; off &= ~(size_t)255;
    int* meta = (int*)(ws + off); off += 256;
    int* ecnt = meta;          // 16
    int* eoff = meta + 16;     // 17
    int* ecur = meta + 33;     // 16
    int* eidx = cnt;           // cnt is free after scan_kernel

    // ---- CSR build ----
    hipMemsetAsync(cnt, 0, (size_t)N_NODES * 4, stream);
    hist_kernel<<<(N_EDGES + 255) / 256, 256, 0, stream>>>(edst, cnt);
    scan_kernel<<<1, 1024, 0, stream>>>(cnt, rowptr, cursor);
    fill_kernel<<<(N_EDGES + 255) / 256, 256, 0, stream>>>(esrc, edst, cursor, csr_src);

    const int nbk = (N_NODES + 255) / 256;

    // ---- layer 1 ----
    gate_kernel<<<NGBLK, 256, 0, stream>>>(x, Wg1, bg1, eidx, gpart);
    hipMemsetAsync(ecnt, 0, 64, stream);
    hist16_kernel<<<nbk, 256, 0, stream>>>(eidx, ecnt);
    scan16_kernel<<<1, 64, 0, stream>>>(ecnt, eoff, ecur);
    scatter16_kernel<<<nbk, 256, 0, stream>>>(eidx, ecur, elist);
    expert_gemm_kernel<<<dim3(N_EXPERT, NYB), 256, 0, stream>>>(x, We1, be1, eoff, elist, A);
    gather_kernel<128, true><<<N_NODES, 128, 0, stream>>>(A, rowptr, csr_src, b1, B);

    // ---- layer 2 ----
    gate_kernel<<<NGBLK, 256, 0, stream>>>(B, Wg2, bg2, eidx, gpart + NGBLK);
    hipMemsetAsync(ecnt, 0, 64, stream);
    hist16_kernel<<<nbk, 256, 0, stream>>>(eidx, ecnt);
    scan16_kernel<<<1, 64, 0, stream>>>(ecnt, eoff, ecur);
    scatter16_kernel<<<nbk, 256, 0, stream>>>(eidx, ecur, elist);
    expert_gemm_kernel<<<dim3(N_EXPERT, NYB), 256, 0, stream>>>(B, We2, be2, eoff, elist, A);
    gather_kernel<128, true><<<N_NODES, 128, 0, stream>>>(A, rowptr, csr_src, b2, B);

    // ---- layer 3 (plain GCNConv) ----
    last_kernel<<<N_NODES / NB, 64, 0, stream>>>(B, Wlast, A);
    gather_kernel<64, false><<<N_NODES, 64, 0, stream>>>(A, rowptr, csr_src, blast, out);

    finalize_kernel<<<1, 1024, 0, stream>>>(gpart, out + (size_t)N_NODES * 64);
}

// Round 10
// 682.978 us; speedup vs baseline: 1.1799x; 1.1799x over previous
//
#include <hip/hip_runtime.h>
#include <math.h>

#define N_NODES 50000
#define N_EDGES 1600000
#define D_IN 128
#define D_HID 128
#define D_OUT 64
#define N_EXPERT 16
#define NB 8     // nodes per block in last kernel
#define GNB 128  // nodes per chunk in expert GEMM (W traffic amortized 2x)
#define NYB 256  // chunk-slots per expert (stride loop handles any skew)
#define NBG 16   // nodes per block in gate kernel (50000 % 16 == 0)
#define NGBLK (N_NODES / NBG)   // 3125 gate blocks per layer
#define XR4 33   // padded x-chunk row stride in float4 (132 floats)
#define NSB ((N_NODES + 255) / 256)   // 196 scan blocks

// ---------------- gate: logits + softmax-std + argmax ------------------------
// One block = 256 threads = NBG(16) nodes. Thread (e = t&15, j = t>>4).
// Wg staged TRANSPOSED in LDS (wgt[e][d], +4 pad); x staged via float4.
__global__ __launch_bounds__(256) void gate_kernel(
    const float* __restrict__ x, const float* __restrict__ Wg, const float* __restrict__ bg,
    int* __restrict__ eidx, float* __restrict__ gpart)
{
    __shared__ float xs[NBG][132];           // +4 pad: bank rotation per row
    __shared__ float wgt[N_EXPERT][132];     // transposed gate weights, +4 pad
    __shared__ float sred[NBG];
    const int n0 = blockIdx.x * NBG;
    const int t = threadIdx.x;

    // Wg: 512 float4 coalesced reads -> transposed scalar LDS stores (2/thread)
    {
        const float4* __restrict__ Wg4 = (const float4*)Wg;
        float4 v = Wg4[t];
        int d = t >> 2, e4 = (t & 3) * 4;
        wgt[e4 + 0][d] = v.x; wgt[e4 + 1][d] = v.y; wgt[e4 + 2][d] = v.z; wgt[e4 + 3][d] = v.w;
        v = Wg4[t + 256];
        d += 64;
        wgt[e4 + 0][d] = v.x; wgt[e4 + 1][d] = v.y; wgt[e4 + 2][d] = v.z; wgt[e4 + 3][d] = v.w;
    }
    // x: 16 rows * 32 float4 = 512 float4 (2/thread), coalesced
    {
        int id = t, row = id >> 5, c4 = id & 31;
        *(float4*)&xs[row][4 * c4] = ((const float4*)(x + (size_t)(n0 + row) * 128))[c4];
        id = t + 256; row = id >> 5; c4 = id & 31;
        *(float4*)&xs[row][4 * c4] = ((const float4*)(x + (size_t)(n0 + row) * 128))[c4];
    }
    __syncthreads();

    const int e = t & 15, j = t >> 4;
    float lg = bg[e];
    #pragma unroll
    for (int d4 = 0; d4 < 32; ++d4) {        // d-ascending FMA order preserved
        const float4 xv = *(const float4*)&xs[j][4 * d4];
        const float4 wv = *(const float4*)&wgt[e][4 * d4];
        lg = fmaf(xv.x, wv.x, lg);
        lg = fmaf(xv.y, wv.y, lg);
        lg = fmaf(xv.z, wv.z, lg);
        lg = fmaf(xv.w, wv.w, lg);
    }

    // 16-lane-group reductions (lanes of one node are contiguous)
    float mx = lg;
    #pragma unroll
    for (int m = 8; m >= 1; m >>= 1) mx = fmaxf(mx, __shfl_xor(mx, m, 16));
    const float ex = expf(lg - mx);
    float se = ex;
    #pragma unroll
    for (int m = 8; m >= 1; m >>= 1) se += __shfl_xor(se, m, 16);
    const float p = ex / se;
    const float dm = p - (1.f / 16.f);
    float var = dm * dm;
    #pragma unroll
    for (int m = 8; m >= 1; m >>= 1) var += __shfl_xor(var, m, 16);

    // argmax over logits (== argmax over softmax), first-index on ties
    float bv = lg; int bi = e;
    #pragma unroll
    for (int m = 8; m >= 1; m >>= 1) {
        const float ov = __shfl_xor(bv, m, 16);
        const int oi = __shfl_xor(bi, m, 16);
        if (ov > bv || (ov == bv && oi < bi)) { bv = ov; bi = oi; }
    }
    if (e == 0) {
        eidx[n0 + j] = bi;
        sred[j] = sqrtf(var * (1.f / 15.f));
    }
    __syncthreads();
    if (t == 0) {
        float s = 0.f;
        #pragma unroll
        for (int jj = 0; jj < NBG; ++jj) s += sred[jj];
        gpart[blockIdx.x] = s;
    }
}

// ---------------- expert bucketing: hist16 -> scan16 -> scatter16 ------------
__global__ __launch_bounds__(256) void hist16_kernel(
    const int* __restrict__ eidx, int* __restrict__ ecnt)
{
    __shared__ int lcnt[N_EXPERT];
    const int t = threadIdx.x;
    const int n = blockIdx.x * 256 + t;
    if (t < N_EXPERT) lcnt[t] = 0;
    __syncthreads();
    if (n < N_NODES) atomicAdd(&lcnt[eidx[n]], 1);
    __syncthreads();
    if (t < N_EXPERT && lcnt[t] > 0) atomicAdd(&ecnt[t], lcnt[t]);
}

__global__ void scan16_kernel(const int* __restrict__ ecnt,
                              int* __restrict__ eoff, int* __restrict__ ecur)
{
    if (threadIdx.x == 0) {
        int s = 0;
        #pragma unroll
        for (int e = 0; e < N_EXPERT; ++e) { eoff[e] = s; ecur[e] = s; s += ecnt[e]; }
        eoff[N_EXPERT] = s;
    }
}

__global__ __launch_bounds__(256) void scatter16_kernel(
    const int* __restrict__ eidx, int* __restrict__ ecur, int* __restrict__ elist)
{
    __shared__ int lcnt[N_EXPERT];
    __shared__ int lbase[N_EXPERT];
    const int t = threadIdx.x;
    const int n = blockIdx.x * 256 + t;
    if (t < N_EXPERT) lcnt[t] = 0;
    __syncthreads();
    int e = 0, lpos = 0;
    if (n < N_NODES) { e = eidx[n]; lpos = atomicAdd(&lcnt[e], 1); }
    __syncthreads();
    if (t < N_EXPERT && lcnt[t] > 0) lbase[t] = atomicAdd(&ecur[t], lcnt[t]);
    __syncthreads();
    if (n < N_NODES) elist[lbase[e] + lpos] = n;
}

// ---------------- per-expert GEMM: y[n] = x[n] @ We[e] + be[e] ---------------
// grid = (16 experts, NYB=256 chunk-slots) + chunk-stride loop (handles the
// layer-2 gating collapse onto few experts).
// GNB=128 nodes/chunk: every wave still streams the full 64 KB We[e] once per
// chunk through L1/L2, but it now serves 2x nodes (W-restream was R6's bound).
// Thread tile: dg = t&31 -> dims 4dg..4dg+3, ng = t>>5 -> nodes 16ng..16ng+15.
// x chunk in LDS padded to 132 floats/row (bank rotation, no 4-way conflict).
// #pragma unroll 2 ONLY (R7 lesson: full unroll -> 256 VGPR + scratch spill).
__global__ __launch_bounds__(256, 2) void expert_gemm_kernel(
    const float* __restrict__ x, const float* __restrict__ We, const float* __restrict__ be,
    const int* __restrict__ eoff, const int* __restrict__ elist, float* __restrict__ y)
{
    __shared__ float xsd[GNB * 132];  // 66 KB padded -> 2 blocks/CU
    const int e = blockIdx.x;
    const int t = threadIdx.x;
    const int row0 = eoff[e];
    const int row1 = eoff[e + 1];

    const int dg = t & 31;   // dims 4*dg .. 4*dg+3
    const int ng = t >> 5;   // nodes 16*ng .. 16*ng+15
    const float4* __restrict__ Wv = (const float4*)(We + (size_t)e * 16384);
    const float4* __restrict__ Xv = (const float4*)xsd;
    const float4 bv = *(const float4*)&be[e * 128 + 4 * dg];

    for (int chunk = blockIdx.y;; chunk += (int)gridDim.y) {
        const int start = row0 + chunk * GNB;
        if (start >= row1) break;   // block-uniform

        // stage 128 node rows of x (float4, coalesced; dummy = first node)
        #pragma unroll
        for (int i = 0; i < 16; ++i) {
            const int id = t + 256 * i;
            const int n = id >> 5;
            const int d4 = id & 31;
            const int idx = start + n;
            const int node = elist[idx < row1 ? idx : start];
            ((float4*)xsd)[n * XR4 + d4] = ((const float4*)(x + (size_t)node * 128))[d4];
        }
        __syncthreads();

        float4 acc[16];
        #pragma unroll
        for (int k = 0; k < 16; ++k) acc[k] = bv;  // bias-init (baseline order)

        #pragma unroll 2
        for (int d4 = 0; d4 < 32; ++d4) {
            float4 w[4];   // W rows 4d4..4d4+3, this thread's 4 dims
            #pragma unroll
            for (int r = 0; r < 4; ++r) w[r] = Wv[(4 * d4 + r) * 32 + dg];
            #pragma unroll
            for (int k = 0; k < 16; ++k) {
                const float4 xv = Xv[(16 * ng + k) * XR4 + d4];
                acc[k].x = fmaf(xv.x, w[0].x, acc[k].x);
                acc[k].y = fmaf(xv.x, w[0].y, acc[k].y);
                acc[k].z = fmaf(xv.x, w[0].z, acc[k].z);
                acc[k].w = fmaf(xv.x, w[0].w, acc[k].w);
                acc[k].x = fmaf(xv.y, w[1].x, acc[k].x);
                acc[k].y = fmaf(xv.y, w[1].y, acc[k].y);
                acc[k].z = fmaf(xv.y, w[1].z, acc[k].z);
                acc[k].w = fmaf(xv.y, w[1].w, acc[k].w);
                acc[k].x = fmaf(xv.z, w[2].x, acc[k].x);
                acc[k].y = fmaf(xv.z, w[2].y, acc[k].y);
                acc[k].z = fmaf(xv.z, w[2].z, acc[k].z);
                acc[k].w = fmaf(xv.z, w[2].w, acc[k].w);
                acc[k].x = fmaf(xv.w, w[3].x, acc[k].x);
                acc[k].y = fmaf(xv.w, w[3].y, acc[k].y);
                acc[k].z = fmaf(xv.w, w[3].z, acc[k].z);
                acc[k].w = fmaf(xv.w, w[3].w, acc[k].w);
            }
        }

        #pragma unroll
        for (int k = 0; k < 16; ++k) {
            const int idx = start + 16 * ng + k;
            if (idx < row1)
                *(float4*)&y[(size_t)elist[idx] * 128 + 4 * dg] = acc[k];
        }

        __syncthreads();   // xsd fully consumed before next-chunk restage
    }
}

// ---------------- final plain linear 128 -> 64, 8 nodes/block ----------------
__global__ __launch_bounds__(64) void last_kernel(
    const float* __restrict__ h, const float* __restrict__ W, float* __restrict__ y)
{
    __shared__ float xs[NB][128];
    const int n0 = blockIdx.x * NB, t = threadIdx.x;
    #pragma unroll
    for (int j = 0; j < NB; ++j) {
        xs[j][t] = h[(size_t)(n0 + j) * 128 + t];
        xs[j][t + 64] = h[(size_t)(n0 + j) * 128 + t + 64];
    }
    __syncthreads();
    float a0 = 0.f, a1 = 0.f, a2 = 0.f, a3 = 0.f;
    float a4 = 0.f, a5 = 0.f, a6 = 0.f, a7 = 0.f;
    #pragma unroll 4
    for (int d = 0; d < 128; ++d) {
        const float w = W[d * 64 + t];
        a0 = fmaf(xs[0][d], w, a0);
        a1 = fmaf(xs[1][d], w, a1);
        a2 = fmaf(xs[2][d], w, a2);
        a3 = fmaf(xs[3][d], w, a3);
        a4 = fmaf(xs[4][d], w, a4);
        a5 = fmaf(xs[5][d], w, a5);
        a6 = fmaf(xs[6][d], w, a6);
        a7 = fmaf(xs[7][d], w, a7);
    }
    y[(size_t)(n0 + 0) * 64 + t] = a0;
    y[(size_t)(n0 + 1) * 64 + t] = a1;
    y[(size_t)(n0 + 2) * 64 + t] = a2;
    y[(size_t)(n0 + 3) * 64 + t] = a3;
    y[(size_t)(n0 + 4) * 64 + t] = a4;
    y[(size_t)(n0 + 5) * 64 + t] = a5;
    y[(size_t)(n0 + 6) * 64 + t] = a6;
    y[(size_t)(n0 + 7) * 64 + t] = a7;
}

// ---------------- CSR build: histogram -> 3-phase scan -> fill ---------------
__global__ void hist_kernel(const int* __restrict__ edst, int* __restrict__ cnt)
{
    const int i = blockIdx.x * blockDim.x + threadIdx.x;
    if (i < N_EDGES) atomicAdd(&cnt[edst[i]], 1);
}

// Phase A: per-block (256-entry tile) sum of cnt, coalesced. 196 blocks.
__global__ __launch_bounds__(256) void presum_kernel(
    const int* __restrict__ cnt, int* __restrict__ bsum)
{
    __shared__ int ws[4];
    const int t = threadIdx.x;
    const int idx = blockIdx.x * 256 + t;
    int v = (idx < N_NODES) ? cnt[idx] : 0;
    #pragma unroll
    for (int m = 32; m >= 1; m >>= 1) v += __shfl_xor(v, m, 64);
    if ((t & 63) == 0) ws[t >> 6] = v;
    __syncthreads();
    if (t == 0) bsum[blockIdx.x] = ws[0] + ws[1] + ws[2] + ws[3];
}

// Phase B: exclusive scan of the 196 block sums (single tiny block).
__global__ __launch_bounds__(256) void scanb_kernel(
    const int* __restrict__ bsum, int* __restrict__ bbase, int* __restrict__ rowptr_last)
{
    __shared__ int buf[256];
    const int t = threadIdx.x;
    const int v = (t < NSB) ? bsum[t] : 0;
    buf[t] = v;
    __syncthreads();
    for (int off = 1; off < 256; off <<= 1) {
        const int add = (t >= off) ? buf[t - off] : 0;
        __syncthreads();
        buf[t] += add;
        __syncthreads();
    }
    if (t < NSB) bbase[t] = buf[t] - v;
    if (t == 255) rowptr_last[0] = buf[255];   // total = N_EDGES
}

// Phase C: per-tile 256-wide LDS scan + block base -> coalesced rowptr/cursor.
__global__ __launch_bounds__(256) void writeback_kernel(
    const int* __restrict__ cnt, const int* __restrict__ bbase,
    int* __restrict__ rowptr, int* __restrict__ cursor)
{
    __shared__ int buf[256];
    const int t = threadIdx.x;
    const int idx = blockIdx.x * 256 + t;
    const int v = (idx < N_NODES) ? cnt[idx] : 0;
    buf[t] = v;
    __syncthreads();
    for (int off = 1; off < 256; off <<= 1) {
        const int add = (t >= off) ? buf[t - off] : 0;
        __syncthreads();
        buf[t] += add;
        __syncthreads();
    }
    const int excl = buf[t] - v + bbase[blockIdx.x];
    if (idx < N_NODES) { rowptr[idx] = excl; cursor[idx] = excl; }
}

// csr_src stored as uint16 (node ids < 65536): halves the scattered-store
// footprint -> halves partial-cacheline writeback amplification, and halves
// gather's csr index reads.
__global__ void fill_kernel(const int* __restrict__ esrc, const int* __restrict__ edst,
                            int* __restrict__ cursor, unsigned short* __restrict__ csr_src)
{
    const int i = blockIdx.x * blockDim.x + threadIdx.x;
    if (i < N_EDGES) {
        const int p = atomicAdd(&cursor[edst[i]], 1);
        csr_src[p] = (unsigned short)esrc[i];
    }
}

// ---------------- gather aggregation: out[n] = bias + sum_{e in row n} h[src] -
template <int D, bool RELU>
__global__ __launch_bounds__(D) void gather_kernel(
    const float* __restrict__ h, const int* __restrict__ rowptr,
    const unsigned short* __restrict__ csr_src, const float* __restrict__ bias,
    float* __restrict__ out)
{
    const int n = blockIdx.x, t = threadIdx.x;
    const int s0 = rowptr[n], s1 = rowptr[n + 1];
    float a0 = bias[t], a1 = 0.f, a2 = 0.f, a3 = 0.f;
    int e = s0;
    for (; e + 3 < s1; e += 4) {
        const int i0 = csr_src[e + 0];
        const int i1 = csr_src[e + 1];
        const int i2 = csr_src[e + 2];
        const int i3 = csr_src[e + 3];
        a0 += h[(size_t)i0 * D + t];
        a1 += h[(size_t)i1 * D + t];
        a2 += h[(size_t)i2 * D + t];
        a3 += h[(size_t)i3 * D + t];
    }
    for (; e < s1; ++e) a0 += h[(size_t)csr_src[e] * D + t];
    float acc = (a0 + a1) + (a2 + a3);
    if (RELU) acc = fmaxf(acc, 0.f);
    out[(size_t)n * D + t] = acc;
}

// ---------------- finalize: reduce 2*NGBLK gate partials + write tail --------
__global__ __launch_bounds__(1024) void finalize_kernel(
    const float* __restrict__ gpart, float* __restrict__ out_tail)
{
    __shared__ float wsum[16];
    const int t = threadIdx.x;
    float s = 0.f;
    for (int i = t; i < 2 * NGBLK; i += 1024) s += gpart[i];
    #pragma unroll
    for (int m = 32; m >= 1; m >>= 1) s += __shfl_xor(s, m, 64);
    if ((t & 63) == 0) wsum[t >> 6] = s;
    __syncthreads();
    if (t == 0) {
        float tot = 0.f;
        #pragma unroll
        for (int w = 0; w < 16; ++w) tot += wsum[w];
        out_tail[0] = tot * (0.5f / (float)N_NODES);
        out_tail[1] = 1.0f;
    }
}

extern "C" void kernel_launch(void* const* d_in, const int* in_sizes, int n_in,
                              void* d_out, int out_size, void* d_ws, size_t ws_size,
                              hipStream_t stream)
{
    const float* x     = (const float*)d_in[0];
    const int*   edge  = (const int*)d_in[1];
    const float* Wg1   = (const float*)d_in[2];
    const float* bg1   = (const float*)d_in[3];
    const float* We1   = (const float*)d_in[4];
    const float* be1   = (const float*)d_in[5];
    const float* b1    = (const float*)d_in[6];
    const float* Wg2   = (const float*)d_in[7];
    const float* bg2   = (const float*)d_in[8];
    const float* We2   = (const float*)d_in[9];
    const float* be2   = (const float*)d_in[10];
    const float* b2    = (const float*)d_in[11];
    const float* Wlast = (const float*)d_in[12];
    const float* blast = (const float*)d_in[13];
    float* out = (float*)d_out;

    const int* esrc = edge;
    const int* edst = edge + N_EDGES;

    char* ws = (char*)d_ws;
    size_t off = 0;
    float* gpart = (float*)(ws + off); off += (size_t)2 * NGBLK * 4 + 252; off &= ~(size_t)255;
    float* A = (float*)(ws + off); off += (size_t)N_NODES * 128 * 4;
    float* B = (float*)(ws + off); off += (size_t)N_NODES * 128 * 4;
    int* rowptr = (int*)(ws + off); off += (size_t)(N_NODES + 1) * 4 + 252; off &= ~(size_t)255;
    int* cnt = (int*)(ws + off); off += (size_t)N_NODES * 4 + 252; off &= ~(size_t)255;
    int* cursor = (int*)(ws + off); off += (size_t)N_NODES * 4 + 252; off &= ~(size_t)255;
    unsigned short* csr_src = (unsigned short*)(ws + off); off += (size_t)N_EDGES * 2 + 252; off &= ~(size_t)255;
    int* elist = (int*)(ws + off); off += (size_t)N_NODES * 4 + 252; off &= ~(size_t)255;
    int* bsum = (int*)(ws + off); off += (size_t)NSB * 4 + 252; off &= ~(size_t)255;
    int* bbase = (int*)(ws + off); off += (size_t)NSB * 4 + 252; off &= ~(size_t)255;
    int* meta = (int*)(ws + off); off += 256;
    int* ecnt = meta;          // 16
    int* eoff = meta + 16;     // 17
    int* ecur = meta + 33;     // 16
    int* eidx = cnt;           // cnt is free after writeback_kernel

    // ---- CSR build ----
    hipMemsetAsync(cnt, 0, (size_t)N_NODES * 4, stream);
    hist_kernel<<<(N_EDGES + 255) / 256, 256, 0, stream>>>(edst, cnt);
    presum_kernel<<<NSB, 256, 0, stream>>>(cnt, bsum);
    scanb_kernel<<<1, 256, 0, stream>>>(bsum, bbase, rowptr + N_NODES);
    writeback_kernel<<<NSB, 256, 0, stream>>>(cnt, bbase, rowptr, cursor);
    fill_kernel<<<(N_EDGES + 255) / 256, 256, 0, stream>>>(esrc, edst, cursor, csr_src);

    const int nbk = (N_NODES + 255) / 256;

    // ---- layer 1 ----
    gate_kernel<<<NGBLK, 256, 0, stream>>>(x, Wg1, bg1, eidx, gpart);
    hipMemsetAsync(ecnt, 0, 64, stream);
    hist16_kernel<<<nbk, 256, 0, stream>>>(eidx, ecnt);
    scan16_kernel<<<1, 64, 0, stream>>>(ecnt, eoff, ecur);
    scatter16_kernel<<<nbk, 256, 0, stream>>>(eidx, ecur, elist);
    expert_gemm_kernel<<<dim3(N_EXPERT, NYB), 256, 0, stream>>>(x, We1, be1, eoff, elist, A);
    gather_kernel<128, true><<<N_NODES, 128, 0, stream>>>(A, rowptr, csr_src, b1, B);

    // ---- layer 2 ----
    gate_kernel<<<NGBLK, 256, 0, stream>>>(B, Wg2, bg2, eidx, gpart + NGBLK);
    hipMemsetAsync(ecnt, 0, 64, stream);
    hist16_kernel<<<nbk, 256, 0, stream>>>(eidx, ecnt);
    scan16_kernel<<<1, 64, 0, stream>>>(ecnt, eoff, ecur);
    scatter16_kernel<<<nbk, 256, 0, stream>>>(eidx, ecur, elist);
    expert_gemm_kernel<<<dim3(N_EXPERT, NYB), 256, 0, stream>>>(B, We2, be2, eoff, elist, A);
    gather_kernel<128, true><<<N_NODES, 128, 0, stream>>>(A, rowptr, csr_src, b2, B);

    // ---- layer 3 (plain GCNConv) ----
    last_kernel<<<N_NODES / NB, 64, 0, stream>>>(B, Wlast, A);
    gather_kernel<64, false><<<N_NODES, 64, 0, stream>>>(A, rowptr, csr_src, blast, out);

    finalize_kernel<<<1, 1024, 0, stream>>>(gpart, out + (size_t)N_NODES * 64);
}

// Round 11
// 519.698 us; speedup vs baseline: 1.5506x; 1.3142x over previous
//
#include <hip/hip_runtime.h>
#include <math.h>

#define N_NODES 50000
#define N_EDGES 1600000
#define D_IN 128
#define D_HID 128
#define D_OUT 64
#define N_EXPERT 16
#define NB 8     // nodes per block in last kernel
#define GNB 128  // nodes per chunk in expert GEMM (W traffic amortized 2x)
#define NYB 256  // chunk-slots per expert (stride loop handles any skew)
#define NBG 16   // nodes per block in gate kernel (50000 % 16 == 0)
#define NGBLK (N_NODES / NBG)   // 3125 gate blocks per layer
#define XR4 33   // padded x-chunk row stride in float4 (132 floats)

// CSR build (bucketed, no global atomics)
#define NBUK 782            // ceil(50000 / 64) coarse buckets (dst >> 6)
#define NFB 250             // phase-1 blocks
#define EPB (N_EDGES / NFB) // 6400 edges per phase-1 block (exact)
#define HM (NBUK * NFB)     // 195500 hist-matrix entries
#define NSB2 ((HM + 255) / 256)  // 764 scan tiles

// ---------------- gate: logits + softmax-std + argmax ------------------------
// One block = 256 threads = NBG(16) nodes. Thread (e = t&15, j = t>>4).
__global__ __launch_bounds__(256) void gate_kernel(
    const float* __restrict__ x, const float* __restrict__ Wg, const float* __restrict__ bg,
    int* __restrict__ eidx, float* __restrict__ gpart)
{
    __shared__ float xs[NBG][132];           // +4 pad: bank rotation per row
    __shared__ float wgt[N_EXPERT][132];     // transposed gate weights, +4 pad
    __shared__ float sred[NBG];
    const int n0 = blockIdx.x * NBG;
    const int t = threadIdx.x;

    // Wg: 512 float4 coalesced reads -> transposed scalar LDS stores (2/thread)
    {
        const float4* __restrict__ Wg4 = (const float4*)Wg;
        float4 v = Wg4[t];
        int d = t >> 2, e4 = (t & 3) * 4;
        wgt[e4 + 0][d] = v.x; wgt[e4 + 1][d] = v.y; wgt[e4 + 2][d] = v.z; wgt[e4 + 3][d] = v.w;
        v = Wg4[t + 256];
        d += 64;
        wgt[e4 + 0][d] = v.x; wgt[e4 + 1][d] = v.y; wgt[e4 + 2][d] = v.z; wgt[e4 + 3][d] = v.w;
    }
    // x: 16 rows * 32 float4 = 512 float4 (2/thread), coalesced
    {
        int id = t, row = id >> 5, c4 = id & 31;
        *(float4*)&xs[row][4 * c4] = ((const float4*)(x + (size_t)(n0 + row) * 128))[c4];
        id = t + 256; row = id >> 5; c4 = id & 31;
        *(float4*)&xs[row][4 * c4] = ((const float4*)(x + (size_t)(n0 + row) * 128))[c4];
    }
    __syncthreads();

    const int e = t & 15, j = t >> 4;
    float lg = bg[e];
    #pragma unroll
    for (int d4 = 0; d4 < 32; ++d4) {        // d-ascending FMA order preserved
        const float4 xv = *(const float4*)&xs[j][4 * d4];
        const float4 wv = *(const float4*)&wgt[e][4 * d4];
        lg = fmaf(xv.x, wv.x, lg);
        lg = fmaf(xv.y, wv.y, lg);
        lg = fmaf(xv.z, wv.z, lg);
        lg = fmaf(xv.w, wv.w, lg);
    }

    // 16-lane-group reductions (lanes of one node are contiguous)
    float mx = lg;
    #pragma unroll
    for (int m = 8; m >= 1; m >>= 1) mx = fmaxf(mx, __shfl_xor(mx, m, 16));
    const float ex = expf(lg - mx);
    float se = ex;
    #pragma unroll
    for (int m = 8; m >= 1; m >>= 1) se += __shfl_xor(se, m, 16);
    const float p = ex / se;
    const float dm = p - (1.f / 16.f);
    float var = dm * dm;
    #pragma unroll
    for (int m = 8; m >= 1; m >>= 1) var += __shfl_xor(var, m, 16);

    // argmax over logits (== argmax over softmax), first-index on ties
    float bv = lg; int bi = e;
    #pragma unroll
    for (int m = 8; m >= 1; m >>= 1) {
        const float ov = __shfl_xor(bv, m, 16);
        const int oi = __shfl_xor(bi, m, 16);
        if (ov > bv || (ov == bv && oi < bi)) { bv = ov; bi = oi; }
    }
    if (e == 0) {
        eidx[n0 + j] = bi;
        sred[j] = sqrtf(var * (1.f / 15.f));
    }
    __syncthreads();
    if (t == 0) {
        float s = 0.f;
        #pragma unroll
        for (int jj = 0; jj < NBG; ++jj) s += sred[jj];
        gpart[blockIdx.x] = s;
    }
}

// ---------------- expert bucketing: hist16 -> scan16 -> scatter16 ------------
__global__ __launch_bounds__(256) void hist16_kernel(
    const int* __restrict__ eidx, int* __restrict__ ecnt)
{
    __shared__ int lcnt[N_EXPERT];
    const int t = threadIdx.x;
    const int n = blockIdx.x * 256 + t;
    if (t < N_EXPERT) lcnt[t] = 0;
    __syncthreads();
    if (n < N_NODES) atomicAdd(&lcnt[eidx[n]], 1);
    __syncthreads();
    if (t < N_EXPERT && lcnt[t] > 0) atomicAdd(&ecnt[t], lcnt[t]);
}

__global__ void scan16_kernel(const int* __restrict__ ecnt,
                              int* __restrict__ eoff, int* __restrict__ ecur)
{
    if (threadIdx.x == 0) {
        int s = 0;
        #pragma unroll
        for (int e = 0; e < N_EXPERT; ++e) { eoff[e] = s; ecur[e] = s; s += ecnt[e]; }
        eoff[N_EXPERT] = s;
    }
}

__global__ __launch_bounds__(256) void scatter16_kernel(
    const int* __restrict__ eidx, int* __restrict__ ecur, int* __restrict__ elist)
{
    __shared__ int lcnt[N_EXPERT];
    __shared__ int lbase[N_EXPERT];
    const int t = threadIdx.x;
    const int n = blockIdx.x * 256 + t;
    if (t < N_EXPERT) lcnt[t] = 0;
    __syncthreads();
    int e = 0, lpos = 0;
    if (n < N_NODES) { e = eidx[n]; lpos = atomicAdd(&lcnt[e], 1); }
    __syncthreads();
    if (t < N_EXPERT && lcnt[t] > 0) lbase[t] = atomicAdd(&ecur[t], lcnt[t]);
    __syncthreads();
    if (n < N_NODES) elist[lbase[e] + lpos] = n;
}

// ---------------- per-expert GEMM: y[n] = x[n] @ We[e] + be[e] ---------------
__global__ __launch_bounds__(256, 2) void expert_gemm_kernel(
    const float* __restrict__ x, const float* __restrict__ We, const float* __restrict__ be,
    const int* __restrict__ eoff, const int* __restrict__ elist, float* __restrict__ y)
{
    __shared__ float xsd[GNB * 132];  // 66 KB padded -> 2 blocks/CU
    const int e = blockIdx.x;
    const int t = threadIdx.x;
    const int row0 = eoff[e];
    const int row1 = eoff[e + 1];

    const int dg = t & 31;   // dims 4*dg .. 4*dg+3
    const int ng = t >> 5;   // nodes 16*ng .. 16*ng+15
    const float4* __restrict__ Wv = (const float4*)(We + (size_t)e * 16384);
    const float4* __restrict__ Xv = (const float4*)xsd;
    const float4 bv = *(const float4*)&be[e * 128 + 4 * dg];

    for (int chunk = blockIdx.y;; chunk += (int)gridDim.y) {
        const int start = row0 + chunk * GNB;
        if (start >= row1) break;   // block-uniform

        // stage 128 node rows of x (float4, coalesced; dummy = first node)
        #pragma unroll
        for (int i = 0; i < 16; ++i) {
            const int id = t + 256 * i;
            const int n = id >> 5;
            const int d4 = id & 31;
            const int idx = start + n;
            const int node = elist[idx < row1 ? idx : start];
            ((float4*)xsd)[n * XR4 + d4] = ((const float4*)(x + (size_t)node * 128))[d4];
        }
        __syncthreads();

        float4 acc[16];
        #pragma unroll
        for (int k = 0; k < 16; ++k) acc[k] = bv;  // bias-init (baseline order)

        #pragma unroll 2
        for (int d4 = 0; d4 < 32; ++d4) {
            float4 w[4];   // W rows 4d4..4d4+3, this thread's 4 dims
            #pragma unroll
            for (int r = 0; r < 4; ++r) w[r] = Wv[(4 * d4 + r) * 32 + dg];
            #pragma unroll
            for (int k = 0; k < 16; ++k) {
                const float4 xv = Xv[(16 * ng + k) * XR4 + d4];
                acc[k].x = fmaf(xv.x, w[0].x, acc[k].x);
                acc[k].y = fmaf(xv.x, w[0].y, acc[k].y);
                acc[k].z = fmaf(xv.x, w[0].z, acc[k].z);
                acc[k].w = fmaf(xv.x, w[0].w, acc[k].w);
                acc[k].x = fmaf(xv.y, w[1].x, acc[k].x);
                acc[k].y = fmaf(xv.y, w[1].y, acc[k].y);
                acc[k].z = fmaf(xv.y, w[1].z, acc[k].z);
                acc[k].w = fmaf(xv.y, w[1].w, acc[k].w);
                acc[k].x = fmaf(xv.z, w[2].x, acc[k].x);
                acc[k].y = fmaf(xv.z, w[2].y, acc[k].y);
                acc[k].z = fmaf(xv.z, w[2].z, acc[k].z);
                acc[k].w = fmaf(xv.z, w[2].w, acc[k].w);
                acc[k].x = fmaf(xv.w, w[3].x, acc[k].x);
                acc[k].y = fmaf(xv.w, w[3].y, acc[k].y);
                acc[k].z = fmaf(xv.w, w[3].z, acc[k].z);
                acc[k].w = fmaf(xv.w, w[3].w, acc[k].w);
            }
        }

        #pragma unroll
        for (int k = 0; k < 16; ++k) {
            const int idx = start + 16 * ng + k;
            if (idx < row1)
                *(float4*)&y[(size_t)elist[idx] * 128 + 4 * dg] = acc[k];
        }

        __syncthreads();   // xsd fully consumed before next-chunk restage
    }
}

// ---------------- final plain linear 128 -> 64, 8 nodes/block ----------------
__global__ __launch_bounds__(64) void last_kernel(
    const float* __restrict__ h, const float* __restrict__ W, float* __restrict__ y)
{
    __shared__ float xs[NB][128];
    const int n0 = blockIdx.x * NB, t = threadIdx.x;
    #pragma unroll
    for (int j = 0; j < NB; ++j) {
        xs[j][t] = h[(size_t)(n0 + j) * 128 + t];
        xs[j][t + 64] = h[(size_t)(n0 + j) * 128 + t + 64];
    }
    __syncthreads();
    float a0 = 0.f, a1 = 0.f, a2 = 0.f, a3 = 0.f;
    float a4 = 0.f, a5 = 0.f, a6 = 0.f, a7 = 0.f;
    #pragma unroll 4
    for (int d = 0; d < 128; ++d) {
        const float w = W[d * 64 + t];
        a0 = fmaf(xs[0][d], w, a0);
        a1 = fmaf(xs[1][d], w, a1);
        a2 = fmaf(xs[2][d], w, a2);
        a3 = fmaf(xs[3][d], w, a3);
        a4 = fmaf(xs[4][d], w, a4);
        a5 = fmaf(xs[5][d], w, a5);
        a6 = fmaf(xs[6][d], w, a6);
        a7 = fmaf(xs[7][d], w, a7);
    }
    y[(size_t)(n0 + 0) * 64 + t] = a0;
    y[(size_t)(n0 + 1) * 64 + t] = a1;
    y[(size_t)(n0 + 2) * 64 + t] = a2;
    y[(size_t)(n0 + 3) * 64 + t] = a3;
    y[(size_t)(n0 + 4) * 64 + t] = a4;
    y[(size_t)(n0 + 5) * 64 + t] = a5;
    y[(size_t)(n0 + 6) * 64 + t] = a6;
    y[(size_t)(n0 + 7) * 64 + t] = a7;
}

// ============== CSR build: bucketed counting sort, NO global atomics =========
// Bucket = dst >> 6 (64 nodes each). Phase 1: per-block LDS hist over buckets.
__global__ __launch_bounds__(256) void bhist_kernel(
    const int* __restrict__ edst, int* __restrict__ hist_g)
{
    __shared__ int lcnt[NBUK];
    const int t = threadIdx.x;
    const int b = blockIdx.x;
    for (int i = t; i < NBUK; i += 256) lcnt[i] = 0;
    __syncthreads();
    const int e0 = b * EPB;
    #pragma unroll 5
    for (int k = 0; k < EPB / 256; ++k)
        atomicAdd(&lcnt[edst[e0 + k * 256 + t] >> 6], 1);
    __syncthreads();
    for (int i = t; i < NBUK; i += 256) hist_g[i * NFB + b] = lcnt[i];
}

// 3-phase exclusive scan over hist_g[HM] (bucket-major order).
__global__ __launch_bounds__(256) void hpre_kernel(
    const int* __restrict__ hist_g, int* __restrict__ tsum)
{
    __shared__ int ws[4];
    const int t = threadIdx.x;
    const int idx = blockIdx.x * 256 + t;
    int v = (idx < HM) ? hist_g[idx] : 0;
    #pragma unroll
    for (int m = 32; m >= 1; m >>= 1) v += __shfl_xor(v, m, 64);
    if ((t & 63) == 0) ws[t >> 6] = v;
    __syncthreads();
    if (t == 0) tsum[blockIdx.x] = ws[0] + ws[1] + ws[2] + ws[3];
}

__global__ __launch_bounds__(1024) void hscan_kernel(
    const int* __restrict__ tsum, int* __restrict__ tbase, int* __restrict__ rowptr_last)
{
    __shared__ int buf[1024];
    const int t = threadIdx.x;
    const int v = (t < NSB2) ? tsum[t] : 0;
    buf[t] = v;
    __syncthreads();
    for (int off = 1; off < 1024; off <<= 1) {
        const int add = (t >= off) ? buf[t - off] : 0;
        __syncthreads();
        buf[t] += add;
        __syncthreads();
    }
    if (t < NSB2) tbase[t] = buf[t] - v;
    if (t == 0) rowptr_last[0] = N_EDGES;
}

__global__ __launch_bounds__(256) void hwb_kernel(
    const int* __restrict__ hist_g, const int* __restrict__ tbase,
    int* __restrict__ base_g)
{
    __shared__ int buf[256];
    const int t = threadIdx.x;
    const int idx = blockIdx.x * 256 + t;
    const int v = (idx < HM) ? hist_g[idx] : 0;
    buf[t] = v;
    __syncthreads();
    for (int off = 1; off < 256; off <<= 1) {
        const int add = (t >= off) ? buf[t - off] : 0;
        __syncthreads();
        buf[t] += add;
        __syncthreads();
    }
    if (idx < HM) base_g[idx] = buf[t] - v + tbase[blockIdx.x];
}

// Phase 2: scatter packed (dst<<16 | src) into bucket-sorted order. Each
// block's writes to a bucket are contiguous runs (~32 edges = 128 B).
__global__ __launch_bounds__(256) void bscatter_kernel(
    const int* __restrict__ esrc, const int* __restrict__ edst,
    const int* __restrict__ base_g, unsigned int* __restrict__ packed)
{
    __shared__ int rcur[NBUK];
    const int t = threadIdx.x;
    const int b = blockIdx.x;
    for (int i = t; i < NBUK; i += 256) rcur[i] = base_g[i * NFB + b];
    __syncthreads();
    const int e0 = b * EPB;
    #pragma unroll 5
    for (int k = 0; k < EPB / 256; ++k) {
        const int i = e0 + k * 256 + t;
        const int src = esrc[i];
        const int dst = edst[i];
        const int p = atomicAdd(&rcur[dst >> 6], 1);
        packed[p] = ((unsigned int)dst << 16) | (unsigned int)src;
    }
}

// Phase 3: per-bucket fine CSR (64 nodes): LDS count -> scan -> rowptr +
// csr_src scatter confined to the bucket's ~4 KB L2-resident region.
__global__ __launch_bounds__(256) void bfine_kernel(
    const unsigned int* __restrict__ packed, const int* __restrict__ base_g,
    int* __restrict__ rowptr, unsigned short* __restrict__ csr_src)
{
    __shared__ int cnt64[64], cur64[64], sexcl[64];
    const int t = threadIdx.x;
    const int j = blockIdx.x;
    const int s0 = base_g[j * NFB];
    const int s1 = (j + 1 < NBUK) ? base_g[(j + 1) * NFB] : N_EDGES;
    if (t < 64) cnt64[t] = 0;
    __syncthreads();
    for (int i = s0 + t; i < s1; i += 256)
        atomicAdd(&cnt64[(packed[i] >> 16) & 63], 1);
    __syncthreads();
    if (t == 0) {
        int run = 0;
        #pragma unroll
        for (int l = 0; l < 64; ++l) { sexcl[l] = run; run += cnt64[l]; }
    }
    __syncthreads();
    if (t < 64) {
        cur64[t] = 0;
        const int n = (j << 6) + t;
        if (n < N_NODES) rowptr[n] = s0 + sexcl[t];
    }
    __syncthreads();
    for (int i = s0 + t; i < s1; i += 256) {
        const unsigned int pk = packed[i];
        const int dl = (pk >> 16) & 63;
        const int p = atomicAdd(&cur64[dl], 1);
        csr_src[s0 + sexcl[dl] + p] = (unsigned short)(pk & 0xffff);
    }
}

// ---------------- gather aggregation: out[n] = bias + sum_{e in row n} h[src] -
template <int D, bool RELU>
__global__ __launch_bounds__(D) void gather_kernel(
    const float* __restrict__ h, const int* __restrict__ rowptr,
    const unsigned short* __restrict__ csr_src, const float* __restrict__ bias,
    float* __restrict__ out)
{
    const int n = blockIdx.x, t = threadIdx.x;
    const int s0 = rowptr[n], s1 = rowptr[n + 1];
    float a0 = bias[t], a1 = 0.f, a2 = 0.f, a3 = 0.f;
    int e = s0;
    for (; e + 3 < s1; e += 4) {
        const int i0 = csr_src[e + 0];
        const int i1 = csr_src[e + 1];
        const int i2 = csr_src[e + 2];
        const int i3 = csr_src[e + 3];
        a0 += h[(size_t)i0 * D + t];
        a1 += h[(size_t)i1 * D + t];
        a2 += h[(size_t)i2 * D + t];
        a3 += h[(size_t)i3 * D + t];
    }
    for (; e < s1; ++e) a0 += h[(size_t)csr_src[e] * D + t];
    float acc = (a0 + a1) + (a2 + a3);
    if (RELU) acc = fmaxf(acc, 0.f);
    out[(size_t)n * D + t] = acc;
}

// ---------------- finalize: reduce 2*NGBLK gate partials + write tail --------
__global__ __launch_bounds__(1024) void finalize_kernel(
    const float* __restrict__ gpart, float* __restrict__ out_tail)
{
    __shared__ float wsum[16];
    const int t = threadIdx.x;
    float s = 0.f;
    for (int i = t; i < 2 * NGBLK; i += 1024) s += gpart[i];
    #pragma unroll
    for (int m = 32; m >= 1; m >>= 1) s += __shfl_xor(s, m, 64);
    if ((t & 63) == 0) wsum[t >> 6] = s;
    __syncthreads();
    if (t == 0) {
        float tot = 0.f;
        #pragma unroll
        for (int w = 0; w < 16; ++w) tot += wsum[w];
        out_tail[0] = tot * (0.5f / (float)N_NODES);
        out_tail[1] = 1.0f;
    }
}

extern "C" void kernel_launch(void* const* d_in, const int* in_sizes, int n_in,
                              void* d_out, int out_size, void* d_ws, size_t ws_size,
                              hipStream_t stream)
{
    const float* x     = (const float*)d_in[0];
    const int*   edge  = (const int*)d_in[1];
    const float* Wg1   = (const float*)d_in[2];
    const float* bg1   = (const float*)d_in[3];
    const float* We1   = (const float*)d_in[4];
    const float* be1   = (const float*)d_in[5];
    const float* b1    = (const float*)d_in[6];
    const float* Wg2   = (const float*)d_in[7];
    const float* bg2   = (const float*)d_in[8];
    const float* We2   = (const float*)d_in[9];
    const float* be2   = (const float*)d_in[10];
    const float* b2    = (const float*)d_in[11];
    const float* Wlast = (const float*)d_in[12];
    const float* blast = (const float*)d_in[13];
    float* out = (float*)d_out;

    const int* esrc = edge;
    const int* edst = edge + N_EDGES;

    char* ws = (char*)d_ws;
    size_t off = 0;
    float* gpart = (float*)(ws + off); off += (size_t)2 * NGBLK * 4 + 252; off &= ~(size_t)255;
    float* A = (float*)(ws + off); off += (size_t)N_NODES * 128 * 4;
    float* B = (float*)(ws + off); off += (size_t)N_NODES * 128 * 4;
    int* rowptr = (int*)(ws + off); off += (size_t)(N_NODES + 1) * 4 + 252; off &= ~(size_t)255;
    int* eidx = (int*)(ws + off); off += (size_t)N_NODES * 4 + 252; off &= ~(size_t)255;
    unsigned short* csr_src = (unsigned short*)(ws + off); off += (size_t)N_EDGES * 2 + 252; off &= ~(size_t)255;
    int* elist = (int*)(ws + off); off += (size_t)N_NODES * 4 + 252; off &= ~(size_t)255;
    int* meta = (int*)(ws + off); off += 256;
    int* ecnt = meta;          // 16
    int* eoff = meta + 16;     // 17
    int* ecur = meta + 33;     // 16

    // CSR temporaries alias A and B (both dead until layer 1 compute):
    unsigned int* packed = (unsigned int*)A;      // 6.4 MB <= 25.6 MB
    int* hist_g = (int*)B;                        // HM ints
    int* base_g = hist_g + HM;                    // HM ints
    int* tsum   = base_g + HM;                    // NSB2 ints
    int* tbase  = tsum + NSB2;                    // NSB2 ints (total ~1.6 MB)

    // ---- CSR build (no global atomics) ----
    bhist_kernel<<<NFB, 256, 0, stream>>>(edst, hist_g);
    hpre_kernel<<<NSB2, 256, 0, stream>>>(hist_g, tsum);
    hscan_kernel<<<1, 1024, 0, stream>>>(tsum, tbase, rowptr + N_NODES);
    hwb_kernel<<<NSB2, 256, 0, stream>>>(hist_g, tbase, base_g);
    bscatter_kernel<<<NFB, 256, 0, stream>>>(esrc, edst, base_g, packed);
    bfine_kernel<<<NBUK, 256, 0, stream>>>(packed, base_g, rowptr, csr_src);

    const int nbk = (N_NODES + 255) / 256;

    // ---- layer 1 ----
    gate_kernel<<<NGBLK, 256, 0, stream>>>(x, Wg1, bg1, eidx, gpart);
    hipMemsetAsync(ecnt, 0, 64, stream);
    hist16_kernel<<<nbk, 256, 0, stream>>>(eidx, ecnt);
    scan16_kernel<<<1, 64, 0, stream>>>(ecnt, eoff, ecur);
    scatter16_kernel<<<nbk, 256, 0, stream>>>(eidx, ecur, elist);
    expert_gemm_kernel<<<dim3(N_EXPERT, NYB), 256, 0, stream>>>(x, We1, be1, eoff, elist, A);
    gather_kernel<128, true><<<N_NODES, 128, 0, stream>>>(A, rowptr, csr_src, b1, B);

    // ---- layer 2 ----
    gate_kernel<<<NGBLK, 256, 0, stream>>>(B, Wg2, bg2, eidx, gpart + NGBLK);
    hipMemsetAsync(ecnt, 0, 64, stream);
    hist16_kernel<<<nbk, 256, 0, stream>>>(eidx, ecnt);
    scan16_kernel<<<1, 64, 0, stream>>>(ecnt, eoff, ecur);
    scatter16_kernel<<<nbk, 256, 0, stream>>>(eidx, ecur, elist);
    expert_gemm_kernel<<<dim3(N_EXPERT, NYB), 256, 0, stream>>>(B, We2, be2, eoff, elist, A);
    gather_kernel<128, true><<<N_NODES, 128, 0, stream>>>(A, rowptr, csr_src, b2, B);

    // ---- layer 3 (plain GCNConv) ----
    last_kernel<<<N_NODES / NB, 64, 0, stream>>>(B, Wlast, A);
    gather_kernel<64, false><<<N_NODES, 64, 0, stream>>>(A, rowptr, csr_src, blast, out);

    finalize_kernel<<<1, 1024, 0, stream>>>(gpart, out + (size_t)N_NODES * 64);
}

// Round 12
// 518.126 us; speedup vs baseline: 1.5553x; 1.0030x over previous
//
#include <hip/hip_runtime.h>
#include <math.h>

#define N_NODES 50000
#define N_EDGES 1600000
#define D_IN 128
#define D_HID 128
#define D_OUT 64
#define N_EXPERT 16
#define NB 8     // nodes per block in last kernel
#define GNB 128  // nodes per chunk in expert GEMM (W traffic amortized 2x)
#define NYB 256  // chunk-slots per expert (stride loop handles any skew)
#define NBG 16   // nodes per block in gate kernel (50000 % 16 == 0)
#define NGBLK (N_NODES / NBG)   // 3125 gate blocks per layer
#define XR4 33   // padded x-chunk row stride in float4 (132 floats)

// CSR build (bucketed, no global atomics)
#define NBUK 782            // ceil(50000 / 64) coarse buckets (dst >> 6)
#define NFB 250             // phase-1 blocks
#define EPB (N_EDGES / NFB) // 6400 edges per phase-1 block (exact)
#define HM (NBUK * NFB)     // 195500 hist-matrix entries
#define NSB2 ((HM + 255) / 256)  // 764 scan tiles

// ---------------- gate: logits + softmax-std + argmax ------------------------
// One block = 256 threads = NBG(16) nodes. Thread (e = t&15, j = t>>4).
__global__ __launch_bounds__(256) void gate_kernel(
    const float* __restrict__ x, const float* __restrict__ Wg, const float* __restrict__ bg,
    int* __restrict__ eidx, float* __restrict__ gpart)
{
    __shared__ float xs[NBG][132];           // +4 pad: bank rotation per row
    __shared__ float wgt[N_EXPERT][132];     // transposed gate weights, +4 pad
    __shared__ float sred[NBG];
    const int n0 = blockIdx.x * NBG;
    const int t = threadIdx.x;

    // Wg: 512 float4 coalesced reads -> transposed scalar LDS stores (2/thread)
    {
        const float4* __restrict__ Wg4 = (const float4*)Wg;
        float4 v = Wg4[t];
        int d = t >> 2, e4 = (t & 3) * 4;
        wgt[e4 + 0][d] = v.x; wgt[e4 + 1][d] = v.y; wgt[e4 + 2][d] = v.z; wgt[e4 + 3][d] = v.w;
        v = Wg4[t + 256];
        d += 64;
        wgt[e4 + 0][d] = v.x; wgt[e4 + 1][d] = v.y; wgt[e4 + 2][d] = v.z; wgt[e4 + 3][d] = v.w;
    }
    // x: 16 rows * 32 float4 = 512 float4 (2/thread), coalesced
    {
        int id = t, row = id >> 5, c4 = id & 31;
        *(float4*)&xs[row][4 * c4] = ((const float4*)(x + (size_t)(n0 + row) * 128))[c4];
        id = t + 256; row = id >> 5; c4 = id & 31;
        *(float4*)&xs[row][4 * c4] = ((const float4*)(x + (size_t)(n0 + row) * 128))[c4];
    }
    __syncthreads();

    const int e = t & 15, j = t >> 4;
    float lg = bg[e];
    #pragma unroll
    for (int d4 = 0; d4 < 32; ++d4) {        // d-ascending FMA order preserved
        const float4 xv = *(const float4*)&xs[j][4 * d4];
        const float4 wv = *(const float4*)&wgt[e][4 * d4];
        lg = fmaf(xv.x, wv.x, lg);
        lg = fmaf(xv.y, wv.y, lg);
        lg = fmaf(xv.z, wv.z, lg);
        lg = fmaf(xv.w, wv.w, lg);
    }

    // 16-lane-group reductions (lanes of one node are contiguous)
    float mx = lg;
    #pragma unroll
    for (int m = 8; m >= 1; m >>= 1) mx = fmaxf(mx, __shfl_xor(mx, m, 16));
    const float ex = expf(lg - mx);
    float se = ex;
    #pragma unroll
    for (int m = 8; m >= 1; m >>= 1) se += __shfl_xor(se, m, 16);
    const float p = ex / se;
    const float dm = p - (1.f / 16.f);
    float var = dm * dm;
    #pragma unroll
    for (int m = 8; m >= 1; m >>= 1) var += __shfl_xor(var, m, 16);

    // argmax over logits (== argmax over softmax), first-index on ties
    float bv = lg; int bi = e;
    #pragma unroll
    for (int m = 8; m >= 1; m >>= 1) {
        const float ov = __shfl_xor(bv, m, 16);
        const int oi = __shfl_xor(bi, m, 16);
        if (ov > bv || (ov == bv && oi < bi)) { bv = ov; bi = oi; }
    }
    if (e == 0) {
        eidx[n0 + j] = bi;
        sred[j] = sqrtf(var * (1.f / 15.f));
    }
    __syncthreads();
    if (t == 0) {
        float s = 0.f;
        #pragma unroll
        for (int jj = 0; jj < NBG; ++jj) s += sred[jj];
        gpart[blockIdx.x] = s;
    }
}

// ---------------- expert bucketing: hist16 -> scan16 -> scatter16 ------------
__global__ __launch_bounds__(256) void hist16_kernel(
    const int* __restrict__ eidx, int* __restrict__ ecnt)
{
    __shared__ int lcnt[N_EXPERT];
    const int t = threadIdx.x;
    const int n = blockIdx.x * 256 + t;
    if (t < N_EXPERT) lcnt[t] = 0;
    __syncthreads();
    if (n < N_NODES) atomicAdd(&lcnt[eidx[n]], 1);
    __syncthreads();
    if (t < N_EXPERT && lcnt[t] > 0) atomicAdd(&ecnt[t], lcnt[t]);
}

__global__ void scan16_kernel(const int* __restrict__ ecnt,
                              int* __restrict__ eoff, int* __restrict__ ecur)
{
    if (threadIdx.x == 0) {
        int s = 0;
        #pragma unroll
        for (int e = 0; e < N_EXPERT; ++e) { eoff[e] = s; ecur[e] = s; s += ecnt[e]; }
        eoff[N_EXPERT] = s;
    }
}

__global__ __launch_bounds__(256) void scatter16_kernel(
    const int* __restrict__ eidx, int* __restrict__ ecur, int* __restrict__ elist)
{
    __shared__ int lcnt[N_EXPERT];
    __shared__ int lbase[N_EXPERT];
    const int t = threadIdx.x;
    const int n = blockIdx.x * 256 + t;
    if (t < N_EXPERT) lcnt[t] = 0;
    __syncthreads();
    int e = 0, lpos = 0;
    if (n < N_NODES) { e = eidx[n]; lpos = atomicAdd(&lcnt[e], 1); }
    __syncthreads();
    if (t < N_EXPERT && lcnt[t] > 0) lbase[t] = atomicAdd(&ecur[t], lcnt[t]);
    __syncthreads();
    if (n < N_NODES) elist[lbase[e] + lpos] = n;
}

// ---------------- per-expert GEMM: y[n] = x[n] @ We[e] + be[e] ---------------
// grid = (16 experts, NYB=256 chunk-slots) + chunk-stride loop.
// W streams from L2 with a REGISTER DOUBLE-BUFFER (wA/wB): iteration i's FMAs
// overlap iteration i+1's 4 L2 loads -- the per-d4 load-latency serialization
// was R11's measured 90% stall. Outer loop pinned to unroll 1 (R7 lesson:
// full unroll hoists all W loads -> 256 VGPR + scratch spill).
__global__ __launch_bounds__(256, 2) void expert_gemm_kernel(
    const float* __restrict__ x, const float* __restrict__ We, const float* __restrict__ be,
    const int* __restrict__ eoff, const int* __restrict__ elist, float* __restrict__ y)
{
    __shared__ float xsd[GNB * 132];  // 66 KB padded -> 2 blocks/CU
    const int e = blockIdx.x;
    const int t = threadIdx.x;
    const int row0 = eoff[e];
    const int row1 = eoff[e + 1];

    const int dg = t & 31;   // dims 4*dg .. 4*dg+3
    const int ng = t >> 5;   // nodes 16*ng .. 16*ng+15
    const float4* __restrict__ Wv = (const float4*)(We + (size_t)e * 16384);
    const float4* __restrict__ Xv = (const float4*)xsd;
    const float4 bv = *(const float4*)&be[e * 128 + 4 * dg];

    for (int chunk = blockIdx.y;; chunk += (int)gridDim.y) {
        const int start = row0 + chunk * GNB;
        if (start >= row1) break;   // block-uniform

        // stage 128 node rows of x (float4, coalesced; dummy = first node)
        #pragma unroll
        for (int i = 0; i < 16; ++i) {
            const int id = t + 256 * i;
            const int n = id >> 5;
            const int d4 = id & 31;
            const int idx = start + n;
            const int node = elist[idx < row1 ? idx : start];
            ((float4*)xsd)[n * XR4 + d4] = ((const float4*)(x + (size_t)node * 128))[d4];
        }
        __syncthreads();

        float4 acc[16];
        #pragma unroll
        for (int k = 0; k < 16; ++k) acc[k] = bv;  // bias-init (baseline order)

        float4 wA[4], wB[4];
        #pragma unroll
        for (int r = 0; r < 4; ++r) wA[r] = Wv[r * 32 + dg];   // rows 0..3

        #pragma unroll 1
        for (int d4 = 0; d4 < 32; d4 += 2) {
            // prefetch rows for d4+1 while computing d4
            #pragma unroll
            for (int r = 0; r < 4; ++r) wB[r] = Wv[(4 * (d4 + 1) + r) * 32 + dg];
            #pragma unroll
            for (int k = 0; k < 16; ++k) {
                const float4 xv = Xv[(16 * ng + k) * XR4 + d4];
                acc[k].x = fmaf(xv.x, wA[0].x, acc[k].x);
                acc[k].y = fmaf(xv.x, wA[0].y, acc[k].y);
                acc[k].z = fmaf(xv.x, wA[0].z, acc[k].z);
                acc[k].w = fmaf(xv.x, wA[0].w, acc[k].w);
                acc[k].x = fmaf(xv.y, wA[1].x, acc[k].x);
                acc[k].y = fmaf(xv.y, wA[1].y, acc[k].y);
                acc[k].z = fmaf(xv.y, wA[1].z, acc[k].z);
                acc[k].w = fmaf(xv.y, wA[1].w, acc[k].w);
                acc[k].x = fmaf(xv.z, wA[2].x, acc[k].x);
                acc[k].y = fmaf(xv.z, wA[2].y, acc[k].y);
                acc[k].z = fmaf(xv.z, wA[2].z, acc[k].z);
                acc[k].w = fmaf(xv.z, wA[2].w, acc[k].w);
                acc[k].x = fmaf(xv.w, wA[3].x, acc[k].x);
                acc[k].y = fmaf(xv.w, wA[3].y, acc[k].y);
                acc[k].z = fmaf(xv.w, wA[3].z, acc[k].z);
                acc[k].w = fmaf(xv.w, wA[3].w, acc[k].w);
            }
            // prefetch rows for d4+2 while computing d4+1
            if (d4 + 2 < 32) {
                #pragma unroll
                for (int r = 0; r < 4; ++r) wA[r] = Wv[(4 * (d4 + 2) + r) * 32 + dg];
            }
            #pragma unroll
            for (int k = 0; k < 16; ++k) {
                const float4 xv = Xv[(16 * ng + k) * XR4 + d4 + 1];
                acc[k].x = fmaf(xv.x, wB[0].x, acc[k].x);
                acc[k].y = fmaf(xv.x, wB[0].y, acc[k].y);
                acc[k].z = fmaf(xv.x, wB[0].z, acc[k].z);
                acc[k].w = fmaf(xv.x, wB[0].w, acc[k].w);
                acc[k].x = fmaf(xv.y, wB[1].x, acc[k].x);
                acc[k].y = fmaf(xv.y, wB[1].y, acc[k].y);
                acc[k].z = fmaf(xv.y, wB[1].z, acc[k].z);
                acc[k].w = fmaf(xv.y, wB[1].w, acc[k].w);
                acc[k].x = fmaf(xv.z, wB[2].x, acc[k].x);
                acc[k].y = fmaf(xv.z, wB[2].y, acc[k].y);
                acc[k].z = fmaf(xv.z, wB[2].z, acc[k].z);
                acc[k].w = fmaf(xv.z, wB[2].w, acc[k].w);
                acc[k].x = fmaf(xv.w, wB[3].x, acc[k].x);
                acc[k].y = fmaf(xv.w, wB[3].y, acc[k].y);
                acc[k].z = fmaf(xv.w, wB[3].z, acc[k].z);
                acc[k].w = fmaf(xv.w, wB[3].w, acc[k].w);
            }
        }

        #pragma unroll
        for (int k = 0; k < 16; ++k) {
            const int idx = start + 16 * ng + k;
            if (idx < row1)
                *(float4*)&y[(size_t)elist[idx] * 128 + 4 * dg] = acc[k];
        }

        __syncthreads();   // xsd fully consumed before next-chunk restage
    }
}

// ---------------- final plain linear 128 -> 64, 8 nodes/block ----------------
__global__ __launch_bounds__(64) void last_kernel(
    const float* __restrict__ h, const float* __restrict__ W, float* __restrict__ y)
{
    __shared__ float xs[NB][128];
    const int n0 = blockIdx.x * NB, t = threadIdx.x;
    #pragma unroll
    for (int j = 0; j < NB; ++j) {
        xs[j][t] = h[(size_t)(n0 + j) * 128 + t];
        xs[j][t + 64] = h[(size_t)(n0 + j) * 128 + t + 64];
    }
    __syncthreads();
    float a0 = 0.f, a1 = 0.f, a2 = 0.f, a3 = 0.f;
    float a4 = 0.f, a5 = 0.f, a6 = 0.f, a7 = 0.f;
    #pragma unroll 4
    for (int d = 0; d < 128; ++d) {
        const float w = W[d * 64 + t];
        a0 = fmaf(xs[0][d], w, a0);
        a1 = fmaf(xs[1][d], w, a1);
        a2 = fmaf(xs[2][d], w, a2);
        a3 = fmaf(xs[3][d], w, a3);
        a4 = fmaf(xs[4][d], w, a4);
        a5 = fmaf(xs[5][d], w, a5);
        a6 = fmaf(xs[6][d], w, a6);
        a7 = fmaf(xs[7][d], w, a7);
    }
    y[(size_t)(n0 + 0) * 64 + t] = a0;
    y[(size_t)(n0 + 1) * 64 + t] = a1;
    y[(size_t)(n0 + 2) * 64 + t] = a2;
    y[(size_t)(n0 + 3) * 64 + t] = a3;
    y[(size_t)(n0 + 4) * 64 + t] = a4;
    y[(size_t)(n0 + 5) * 64 + t] = a5;
    y[(size_t)(n0 + 6) * 64 + t] = a6;
    y[(size_t)(n0 + 7) * 64 + t] = a7;
}

// ============== CSR build: bucketed counting sort, NO global atomics =========
__global__ __launch_bounds__(256) void bhist_kernel(
    const int* __restrict__ edst, int* __restrict__ hist_g)
{
    __shared__ int lcnt[NBUK];
    const int t = threadIdx.x;
    const int b = blockIdx.x;
    for (int i = t; i < NBUK; i += 256) lcnt[i] = 0;
    __syncthreads();
    const int e0 = b * EPB;
    #pragma unroll 5
    for (int k = 0; k < EPB / 256; ++k)
        atomicAdd(&lcnt[edst[e0 + k * 256 + t] >> 6], 1);
    __syncthreads();
    for (int i = t; i < NBUK; i += 256) hist_g[i * NFB + b] = lcnt[i];
}

__global__ __launch_bounds__(256) void hpre_kernel(
    const int* __restrict__ hist_g, int* __restrict__ tsum)
{
    __shared__ int ws[4];
    const int t = threadIdx.x;
    const int idx = blockIdx.x * 256 + t;
    int v = (idx < HM) ? hist_g[idx] : 0;
    #pragma unroll
    for (int m = 32; m >= 1; m >>= 1) v += __shfl_xor(v, m, 64);
    if ((t & 63) == 0) ws[t >> 6] = v;
    __syncthreads();
    if (t == 0) tsum[blockIdx.x] = ws[0] + ws[1] + ws[2] + ws[3];
}

__global__ __launch_bounds__(1024) void hscan_kernel(
    const int* __restrict__ tsum, int* __restrict__ tbase, int* __restrict__ rowptr_last)
{
    __shared__ int buf[1024];
    const int t = threadIdx.x;
    const int v = (t < NSB2) ? tsum[t] : 0;
    buf[t] = v;
    __syncthreads();
    for (int off = 1; off < 1024; off <<= 1) {
        const int add = (t >= off) ? buf[t - off] : 0;
        __syncthreads();
        buf[t] += add;
        __syncthreads();
    }
    if (t < NSB2) tbase[t] = buf[t] - v;
    if (t == 0) rowptr_last[0] = N_EDGES;
}

__global__ __launch_bounds__(256) void hwb_kernel(
    const int* __restrict__ hist_g, const int* __restrict__ tbase,
    int* __restrict__ base_g)
{
    __shared__ int buf[256];
    const int t = threadIdx.x;
    const int idx = blockIdx.x * 256 + t;
    const int v = (idx < HM) ? hist_g[idx] : 0;
    buf[t] = v;
    __syncthreads();
    for (int off = 1; off < 256; off <<= 1) {
        const int add = (t >= off) ? buf[t - off] : 0;
        __syncthreads();
        buf[t] += add;
        __syncthreads();
    }
    if (idx < HM) base_g[idx] = buf[t] - v + tbase[blockIdx.x];
}

__global__ __launch_bounds__(256) void bscatter_kernel(
    const int* __restrict__ esrc, const int* __restrict__ edst,
    const int* __restrict__ base_g, unsigned int* __restrict__ packed)
{
    __shared__ int rcur[NBUK];
    const int t = threadIdx.x;
    const int b = blockIdx.x;
    for (int i = t; i < NBUK; i += 256) rcur[i] = base_g[i * NFB + b];
    __syncthreads();
    const int e0 = b * EPB;
    #pragma unroll 5
    for (int k = 0; k < EPB / 256; ++k) {
        const int i = e0 + k * 256 + t;
        const int src = esrc[i];
        const int dst = edst[i];
        const int p = atomicAdd(&rcur[dst >> 6], 1);
        packed[p] = ((unsigned int)dst << 16) | (unsigned int)src;
    }
}

__global__ __launch_bounds__(256) void bfine_kernel(
    const unsigned int* __restrict__ packed, const int* __restrict__ base_g,
    int* __restrict__ rowptr, unsigned short* __restrict__ csr_src)
{
    __shared__ int cnt64[64], cur64[64], sexcl[64];
    const int t = threadIdx.x;
    const int j = blockIdx.x;
    const int s0 = base_g[j * NFB];
    const int s1 = (j + 1 < NBUK) ? base_g[(j + 1) * NFB] : N_EDGES;
    if (t < 64) cnt64[t] = 0;
    __syncthreads();
    for (int i = s0 + t; i < s1; i += 256)
        atomicAdd(&cnt64[(packed[i] >> 16) & 63], 1);
    __syncthreads();
    if (t == 0) {
        int run = 0;
        #pragma unroll
        for (int l = 0; l < 64; ++l) { sexcl[l] = run; run += cnt64[l]; }
    }
    __syncthreads();
    if (t < 64) {
        cur64[t] = 0;
        const int n = (j << 6) + t;
        if (n < N_NODES) rowptr[n] = s0 + sexcl[t];
    }
    __syncthreads();
    for (int i = s0 + t; i < s1; i += 256) {
        const unsigned int pk = packed[i];
        const int dl = (pk >> 16) & 63;
        const int p = atomicAdd(&cur64[dl], 1);
        csr_src[s0 + sexcl[dl] + p] = (unsigned short)(pk & 0xffff);
    }
}

// ---------------- gather aggregation: out[n] = bias + sum_{e in row n} h[src] -
template <int D, bool RELU>
__global__ __launch_bounds__(D) void gather_kernel(
    const float* __restrict__ h, const int* __restrict__ rowptr,
    const unsigned short* __restrict__ csr_src, const float* __restrict__ bias,
    float* __restrict__ out)
{
    const int n = blockIdx.x, t = threadIdx.x;
    const int s0 = rowptr[n], s1 = rowptr[n + 1];
    float a0 = bias[t], a1 = 0.f, a2 = 0.f, a3 = 0.f;
    int e = s0;
    for (; e + 3 < s1; e += 4) {
        const int i0 = csr_src[e + 0];
        const int i1 = csr_src[e + 1];
        const int i2 = csr_src[e + 2];
        const int i3 = csr_src[e + 3];
        a0 += h[(size_t)i0 * D + t];
        a1 += h[(size_t)i1 * D + t];
        a2 += h[(size_t)i2 * D + t];
        a3 += h[(size_t)i3 * D + t];
    }
    for (; e < s1; ++e) a0 += h[(size_t)csr_src[e] * D + t];
    float acc = (a0 + a1) + (a2 + a3);
    if (RELU) acc = fmaxf(acc, 0.f);
    out[(size_t)n * D + t] = acc;
}

// ---------------- finalize: reduce 2*NGBLK gate partials + write tail --------
__global__ __launch_bounds__(1024) void finalize_kernel(
    const float* __restrict__ gpart, float* __restrict__ out_tail)
{
    __shared__ float wsum[16];
    const int t = threadIdx.x;
    float s = 0.f;
    for (int i = t; i < 2 * NGBLK; i += 1024) s += gpart[i];
    #pragma unroll
    for (int m = 32; m >= 1; m >>= 1) s += __shfl_xor(s, m, 64);
    if ((t & 63) == 0) wsum[t >> 6] = s;
    __syncthreads();
    if (t == 0) {
        float tot = 0.f;
        #pragma unroll
        for (int w = 0; w < 16; ++w) tot += wsum[w];
        out_tail[0] = tot * (0.5f / (float)N_NODES);
        out_tail[1] = 1.0f;
    }
}

extern "C" void kernel_launch(void* const* d_in, const int* in_sizes, int n_in,
                              void* d_out, int out_size, void* d_ws, size_t ws_size,
                              hipStream_t stream)
{
    const float* x     = (const float*)d_in[0];
    const int*   edge  = (const int*)d_in[1];
    const float* Wg1   = (const float*)d_in[2];
    const float* bg1   = (const float*)d_in[3];
    const float* We1   = (const float*)d_in[4];
    const float* be1   = (const float*)d_in[5];
    const float* b1    = (const float*)d_in[6];
    const float* Wg2   = (const float*)d_in[7];
    const float* bg2   = (const float*)d_in[8];
    const float* We2   = (const float*)d_in[9];
    const float* be2   = (const float*)d_in[10];
    const float* b2    = (const float*)d_in[11];
    const float* Wlast = (const float*)d_in[12];
    const float* blast = (const float*)d_in[13];
    float* out = (float*)d_out;

    const int* esrc = edge;
    const int* edst = edge + N_EDGES;

    char* ws = (char*)d_ws;
    size_t off = 0;
    float* gpart = (float*)(ws + off); off += (size_t)2 * NGBLK * 4 + 252; off &= ~(size_t)255;
    float* A = (float*)(ws + off); off += (size_t)N_NODES * 128 * 4;
    float* B = (float*)(ws + off); off += (size_t)N_NODES * 128 * 4;
    int* rowptr = (int*)(ws + off); off += (size_t)(N_NODES + 1) * 4 + 252; off &= ~(size_t)255;
    int* eidx = (int*)(ws + off); off += (size_t)N_NODES * 4 + 252; off &= ~(size_t)255;
    unsigned short* csr_src = (unsigned short*)(ws + off); off += (size_t)N_EDGES * 2 + 252; off &= ~(size_t)255;
    int* elist = (int*)(ws + off); off += (size_t)N_NODES * 4 + 252; off &= ~(size_t)255;
    int* meta = (int*)(ws + off); off += 256;
    int* ecnt = meta;          // 16
    int* eoff = meta + 16;     // 17
    int* ecur = meta + 33;     // 16

    // CSR temporaries alias A and B (both dead until layer 1 compute):
    unsigned int* packed = (unsigned int*)A;      // 6.4 MB <= 25.6 MB
    int* hist_g = (int*)B;                        // HM ints
    int* base_g = hist_g + HM;                    // HM ints
    int* tsum   = base_g + HM;                    // NSB2 ints
    int* tbase  = tsum + NSB2;                    // NSB2 ints (total ~1.6 MB)

    // ---- CSR build (no global atomics) ----
    bhist_kernel<<<NFB, 256, 0, stream>>>(edst, hist_g);
    hpre_kernel<<<NSB2, 256, 0, stream>>>(hist_g, tsum);
    hscan_kernel<<<1, 1024, 0, stream>>>(tsum, tbase, rowptr + N_NODES);
    hwb_kernel<<<NSB2, 256, 0, stream>>>(hist_g, tbase, base_g);
    bscatter_kernel<<<NFB, 256, 0, stream>>>(esrc, edst, base_g, packed);
    bfine_kernel<<<NBUK, 256, 0, stream>>>(packed, base_g, rowptr, csr_src);

    const int nbk = (N_NODES + 255) / 256;

    // ---- layer 1 ----
    gate_kernel<<<NGBLK, 256, 0, stream>>>(x, Wg1, bg1, eidx, gpart);
    hipMemsetAsync(ecnt, 0, 64, stream);
    hist16_kernel<<<nbk, 256, 0, stream>>>(eidx, ecnt);
    scan16_kernel<<<1, 64, 0, stream>>>(ecnt, eoff, ecur);
    scatter16_kernel<<<nbk, 256, 0, stream>>>(eidx, ecur, elist);
    expert_gemm_kernel<<<dim3(N_EXPERT, NYB), 256, 0, stream>>>(x, We1, be1, eoff, elist, A);
    gather_kernel<128, true><<<N_NODES, 128, 0, stream>>>(A, rowptr, csr_src, b1, B);

    // ---- layer 2 ----
    gate_kernel<<<NGBLK, 256, 0, stream>>>(B, Wg2, bg2, eidx, gpart + NGBLK);
    hipMemsetAsync(ecnt, 0, 64, stream);
    hist16_kernel<<<nbk, 256, 0, stream>>>(eidx, ecnt);
    scan16_kernel<<<1, 64, 0, stream>>>(ecnt, eoff, ecur);
    scatter16_kernel<<<nbk, 256, 0, stream>>>(eidx, ecur, elist);
    expert_gemm_kernel<<<dim3(N_EXPERT, NYB), 256, 0, stream>>>(B, We2, be2, eoff, elist, A);
    gather_kernel<128, true><<<N_NODES, 128, 0, stream>>>(A, rowptr, csr_src, b2, B);

    // ---- layer 3 (plain GCNConv) ----
    last_kernel<<<N_NODES / NB, 64, 0, stream>>>(B, Wlast, A);
    gather_kernel<64, false><<<N_NODES, 64, 0, stream>>>(A, rowptr, csr_src, blast, out);

    finalize_kernel<<<1, 1024, 0, stream>>>(gpart, out + (size_t)N_NODES * 64);
}

// Round 13
// 473.758 us; speedup vs baseline: 1.7010x; 1.0937x over previous
//
#include <hip/hip_runtime.h>
#include <math.h>

#define N_NODES 50000
#define N_EDGES 1600000
#define D_IN 128
#define D_HID 128
#define D_OUT 64
#define N_EXPERT 16
#define NB 8     // nodes per block in last kernel
#define GNB 128  // nodes per chunk in expert GEMM (W traffic amortized 2x)
#define NYB 256  // chunk-slots per expert (stride loop handles any skew)
#define NBG 16   // nodes per block in gate kernel (50000 % 16 == 0)
#define NGBLK (N_NODES / NBG)   // 3125 gate blocks per layer
#define XR4 33   // padded x-chunk row stride in float4 (132 floats)

// CSR build (bucketed, no global atomics)
#define NBUK 782            // ceil(50000 / 64) coarse buckets (dst >> 6)
#define NFB 250             // phase-1 blocks
#define EPB (N_EDGES / NFB) // 6400 edges per phase-1 block (exact)
#define HM (NBUK * NFB)     // 195500 hist-matrix entries
#define NSB2 ((HM + 255) / 256)  // 764 scan tiles

// bf16 helpers (round-to-nearest-even)
__device__ __forceinline__ unsigned short f2bf(float f) {
    unsigned int u = __float_as_uint(f);
    return (unsigned short)((u + 0x7fffu + ((u >> 16) & 1u)) >> 16);
}
__device__ __forceinline__ float bf2f(unsigned short h) {
    return __uint_as_float((unsigned int)h << 16);
}

// ---------------- gate: logits + softmax-std + argmax ------------------------
// One block = 256 threads = NBG(16) nodes. Thread (e = t&15, j = t>>4).
__global__ __launch_bounds__(256) void gate_kernel(
    const float* __restrict__ x, const float* __restrict__ Wg, const float* __restrict__ bg,
    int* __restrict__ eidx, float* __restrict__ gpart)
{
    __shared__ float xs[NBG][132];           // +4 pad: bank rotation per row
    __shared__ float wgt[N_EXPERT][132];     // transposed gate weights, +4 pad
    __shared__ float sred[NBG];
    const int n0 = blockIdx.x * NBG;
    const int t = threadIdx.x;

    // Wg: 512 float4 coalesced reads -> transposed scalar LDS stores (2/thread)
    {
        const float4* __restrict__ Wg4 = (const float4*)Wg;
        float4 v = Wg4[t];
        int d = t >> 2, e4 = (t & 3) * 4;
        wgt[e4 + 0][d] = v.x; wgt[e4 + 1][d] = v.y; wgt[e4 + 2][d] = v.z; wgt[e4 + 3][d] = v.w;
        v = Wg4[t + 256];
        d += 64;
        wgt[e4 + 0][d] = v.x; wgt[e4 + 1][d] = v.y; wgt[e4 + 2][d] = v.z; wgt[e4 + 3][d] = v.w;
    }
    // x: 16 rows * 32 float4 = 512 float4 (2/thread), coalesced
    {
        int id = t, row = id >> 5, c4 = id & 31;
        *(float4*)&xs[row][4 * c4] = ((const float4*)(x + (size_t)(n0 + row) * 128))[c4];
        id = t + 256; row = id >> 5; c4 = id & 31;
        *(float4*)&xs[row][4 * c4] = ((const float4*)(x + (size_t)(n0 + row) * 128))[c4];
    }
    __syncthreads();

    const int e = t & 15, j = t >> 4;
    float lg = bg[e];
    #pragma unroll
    for (int d4 = 0; d4 < 32; ++d4) {        // d-ascending FMA order preserved
        const float4 xv = *(const float4*)&xs[j][4 * d4];
        const float4 wv = *(const float4*)&wgt[e][4 * d4];
        lg = fmaf(xv.x, wv.x, lg);
        lg = fmaf(xv.y, wv.y, lg);
        lg = fmaf(xv.z, wv.z, lg);
        lg = fmaf(xv.w, wv.w, lg);
    }

    // 16-lane-group reductions (lanes of one node are contiguous)
    float mx = lg;
    #pragma unroll
    for (int m = 8; m >= 1; m >>= 1) mx = fmaxf(mx, __shfl_xor(mx, m, 16));
    const float ex = expf(lg - mx);
    float se = ex;
    #pragma unroll
    for (int m = 8; m >= 1; m >>= 1) se += __shfl_xor(se, m, 16);
    const float p = ex / se;
    const float dm = p - (1.f / 16.f);
    float var = dm * dm;
    #pragma unroll
    for (int m = 8; m >= 1; m >>= 1) var += __shfl_xor(var, m, 16);

    // argmax over logits (== argmax over softmax), first-index on ties
    float bv = lg; int bi = e;
    #pragma unroll
    for (int m = 8; m >= 1; m >>= 1) {
        const float ov = __shfl_xor(bv, m, 16);
        const int oi = __shfl_xor(bi, m, 16);
        if (ov > bv || (ov == bv && oi < bi)) { bv = ov; bi = oi; }
    }
    if (e == 0) {
        eidx[n0 + j] = bi;
        sred[j] = sqrtf(var * (1.f / 15.f));
    }
    __syncthreads();
    if (t == 0) {
        float s = 0.f;
        #pragma unroll
        for (int jj = 0; jj < NBG; ++jj) s += sred[jj];
        gpart[blockIdx.x] = s;
    }
}

// ---------------- expert bucketing: hist16 -> scan16 -> scatter16 ------------
__global__ __launch_bounds__(256) void hist16_kernel(
    const int* __restrict__ eidx, int* __restrict__ ecnt)
{
    __shared__ int lcnt[N_EXPERT];
    const int t = threadIdx.x;
    const int n = blockIdx.x * 256 + t;
    if (t < N_EXPERT) lcnt[t] = 0;
    __syncthreads();
    if (n < N_NODES) atomicAdd(&lcnt[eidx[n]], 1);
    __syncthreads();
    if (t < N_EXPERT && lcnt[t] > 0) atomicAdd(&ecnt[t], lcnt[t]);
}

__global__ void scan16_kernel(const int* __restrict__ ecnt,
                              int* __restrict__ eoff, int* __restrict__ ecur)
{
    if (threadIdx.x == 0) {
        int s = 0;
        #pragma unroll
        for (int e = 0; e < N_EXPERT; ++e) { eoff[e] = s; ecur[e] = s; s += ecnt[e]; }
        eoff[N_EXPERT] = s;
    }
}

__global__ __launch_bounds__(256) void scatter16_kernel(
    const int* __restrict__ eidx, int* __restrict__ ecur, int* __restrict__ elist)
{
    __shared__ int lcnt[N_EXPERT];
    __shared__ int lbase[N_EXPERT];
    const int t = threadIdx.x;
    const int n = blockIdx.x * 256 + t;
    if (t < N_EXPERT) lcnt[t] = 0;
    __syncthreads();
    int e = 0, lpos = 0;
    if (n < N_NODES) { e = eidx[n]; lpos = atomicAdd(&lcnt[e], 1); }
    __syncthreads();
    if (t < N_EXPERT && lcnt[t] > 0) lbase[t] = atomicAdd(&ecur[t], lcnt[t]);
    __syncthreads();
    if (n < N_NODES) elist[lbase[e] + lpos] = n;
}

// ---------------- per-expert GEMM: y[n] = x[n] @ We[e] + be[e] ---------------
// Same tile as R12; OUTPUT NOW BF16 (rows 256 B) -- the gathers are
// bandwidth-bound on these rows, so halving bytes halves their traffic.
// fp32 accumulation + d-ascending order unchanged; rounding only at store.
__global__ __launch_bounds__(256, 2) void expert_gemm_kernel(
    const float* __restrict__ x, const float* __restrict__ We, const float* __restrict__ be,
    const int* __restrict__ eoff, const int* __restrict__ elist,
    unsigned short* __restrict__ y)
{
    __shared__ float xsd[GNB * 132];  // 66 KB padded -> 2 blocks/CU
    const int e = blockIdx.x;
    const int t = threadIdx.x;
    const int row0 = eoff[e];
    const int row1 = eoff[e + 1];

    const int dg = t & 31;   // dims 4*dg .. 4*dg+3
    const int ng = t >> 5;   // nodes 16*ng .. 16*ng+15
    const float4* __restrict__ Wv = (const float4*)(We + (size_t)e * 16384);
    const float4* __restrict__ Xv = (const float4*)xsd;
    const float4 bv = *(const float4*)&be[e * 128 + 4 * dg];

    for (int chunk = blockIdx.y;; chunk += (int)gridDim.y) {
        const int start = row0 + chunk * GNB;
        if (start >= row1) break;   // block-uniform

        // stage 128 node rows of x (float4, coalesced; dummy = first node)
        #pragma unroll
        for (int i = 0; i < 16; ++i) {
            const int id = t + 256 * i;
            const int n = id >> 5;
            const int d4 = id & 31;
            const int idx = start + n;
            const int node = elist[idx < row1 ? idx : start];
            ((float4*)xsd)[n * XR4 + d4] = ((const float4*)(x + (size_t)node * 128))[d4];
        }
        __syncthreads();

        float4 acc[16];
        #pragma unroll
        for (int k = 0; k < 16; ++k) acc[k] = bv;  // bias-init (baseline order)

        float4 wA[4], wB[4];
        #pragma unroll
        for (int r = 0; r < 4; ++r) wA[r] = Wv[r * 32 + dg];   // rows 0..3

        #pragma unroll 1
        for (int d4 = 0; d4 < 32; d4 += 2) {
            #pragma unroll
            for (int r = 0; r < 4; ++r) wB[r] = Wv[(4 * (d4 + 1) + r) * 32 + dg];
            #pragma unroll
            for (int k = 0; k < 16; ++k) {
                const float4 xv = Xv[(16 * ng + k) * XR4 + d4];
                acc[k].x = fmaf(xv.x, wA[0].x, acc[k].x);
                acc[k].y = fmaf(xv.x, wA[0].y, acc[k].y);
                acc[k].z = fmaf(xv.x, wA[0].z, acc[k].z);
                acc[k].w = fmaf(xv.x, wA[0].w, acc[k].w);
                acc[k].x = fmaf(xv.y, wA[1].x, acc[k].x);
                acc[k].y = fmaf(xv.y, wA[1].y, acc[k].y);
                acc[k].z = fmaf(xv.y, wA[1].z, acc[k].z);
                acc[k].w = fmaf(xv.y, wA[1].w, acc[k].w);
                acc[k].x = fmaf(xv.z, wA[2].x, acc[k].x);
                acc[k].y = fmaf(xv.z, wA[2].y, acc[k].y);
                acc[k].z = fmaf(xv.z, wA[2].z, acc[k].z);
                acc[k].w = fmaf(xv.z, wA[2].w, acc[k].w);
                acc[k].x = fmaf(xv.w, wA[3].x, acc[k].x);
                acc[k].y = fmaf(xv.w, wA[3].y, acc[k].y);
                acc[k].z = fmaf(xv.w, wA[3].z, acc[k].z);
                acc[k].w = fmaf(xv.w, wA[3].w, acc[k].w);
            }
            if (d4 + 2 < 32) {
                #pragma unroll
                for (int r = 0; r < 4; ++r) wA[r] = Wv[(4 * (d4 + 2) + r) * 32 + dg];
            }
            #pragma unroll
            for (int k = 0; k < 16; ++k) {
                const float4 xv = Xv[(16 * ng + k) * XR4 + d4 + 1];
                acc[k].x = fmaf(xv.x, wB[0].x, acc[k].x);
                acc[k].y = fmaf(xv.x, wB[0].y, acc[k].y);
                acc[k].z = fmaf(xv.x, wB[0].z, acc[k].z);
                acc[k].w = fmaf(xv.x, wB[0].w, acc[k].w);
                acc[k].x = fmaf(xv.y, wB[1].x, acc[k].x);
                acc[k].y = fmaf(xv.y, wB[1].y, acc[k].y);
                acc[k].z = fmaf(xv.y, wB[1].z, acc[k].z);
                acc[k].w = fmaf(xv.y, wB[1].w, acc[k].w);
                acc[k].x = fmaf(xv.z, wB[2].x, acc[k].x);
                acc[k].y = fmaf(xv.z, wB[2].y, acc[k].y);
                acc[k].z = fmaf(xv.z, wB[2].z, acc[k].z);
                acc[k].w = fmaf(xv.z, wB[2].w, acc[k].w);
                acc[k].x = fmaf(xv.w, wB[3].x, acc[k].x);
                acc[k].y = fmaf(xv.w, wB[3].y, acc[k].y);
                acc[k].z = fmaf(xv.w, wB[3].z, acc[k].z);
                acc[k].w = fmaf(xv.w, wB[3].w, acc[k].w);
            }
        }

        #pragma unroll
        for (int k = 0; k < 16; ++k) {
            const int idx = start + 16 * ng + k;
            if (idx < row1) {
                ushort4 o;
                o.x = f2bf(acc[k].x); o.y = f2bf(acc[k].y);
                o.z = f2bf(acc[k].z); o.w = f2bf(acc[k].w);
                *(ushort4*)&y[(size_t)elist[idx] * 128 + 4 * dg] = o;
            }
        }

        __syncthreads();   // xsd fully consumed before next-chunk restage
    }
}

// ---------------- final plain linear 128 -> 64, 8 nodes/block (bf16 out) -----
__global__ __launch_bounds__(64) void last_kernel(
    const float* __restrict__ h, const float* __restrict__ W,
    unsigned short* __restrict__ y)
{
    __shared__ float xs[NB][128];
    const int n0 = blockIdx.x * NB, t = threadIdx.x;
    #pragma unroll
    for (int j = 0; j < NB; ++j) {
        xs[j][t] = h[(size_t)(n0 + j) * 128 + t];
        xs[j][t + 64] = h[(size_t)(n0 + j) * 128 + t + 64];
    }
    __syncthreads();
    float a0 = 0.f, a1 = 0.f, a2 = 0.f, a3 = 0.f;
    float a4 = 0.f, a5 = 0.f, a6 = 0.f, a7 = 0.f;
    #pragma unroll 4
    for (int d = 0; d < 128; ++d) {
        const float w = W[d * 64 + t];
        a0 = fmaf(xs[0][d], w, a0);
        a1 = fmaf(xs[1][d], w, a1);
        a2 = fmaf(xs[2][d], w, a2);
        a3 = fmaf(xs[3][d], w, a3);
        a4 = fmaf(xs[4][d], w, a4);
        a5 = fmaf(xs[5][d], w, a5);
        a6 = fmaf(xs[6][d], w, a6);
        a7 = fmaf(xs[7][d], w, a7);
    }
    y[(size_t)(n0 + 0) * 64 + t] = f2bf(a0);
    y[(size_t)(n0 + 1) * 64 + t] = f2bf(a1);
    y[(size_t)(n0 + 2) * 64 + t] = f2bf(a2);
    y[(size_t)(n0 + 3) * 64 + t] = f2bf(a3);
    y[(size_t)(n0 + 4) * 64 + t] = f2bf(a4);
    y[(size_t)(n0 + 5) * 64 + t] = f2bf(a5);
    y[(size_t)(n0 + 6) * 64 + t] = f2bf(a6);
    y[(size_t)(n0 + 7) * 64 + t] = f2bf(a7);
}

// ============== CSR build: bucketed counting sort, NO global atomics =========
__global__ __launch_bounds__(256) void bhist_kernel(
    const int* __restrict__ edst, int* __restrict__ hist_g)
{
    __shared__ int lcnt[NBUK];
    const int t = threadIdx.x;
    const int b = blockIdx.x;
    for (int i = t; i < NBUK; i += 256) lcnt[i] = 0;
    __syncthreads();
    const int e0 = b * EPB;
    #pragma unroll 5
    for (int k = 0; k < EPB / 256; ++k)
        atomicAdd(&lcnt[edst[e0 + k * 256 + t] >> 6], 1);
    __syncthreads();
    for (int i = t; i < NBUK; i += 256) hist_g[i * NFB + b] = lcnt[i];
}

__global__ __launch_bounds__(256) void hpre_kernel(
    const int* __restrict__ hist_g, int* __restrict__ tsum)
{
    __shared__ int ws[4];
    const int t = threadIdx.x;
    const int idx = blockIdx.x * 256 + t;
    int v = (idx < HM) ? hist_g[idx] : 0;
    #pragma unroll
    for (int m = 32; m >= 1; m >>= 1) v += __shfl_xor(v, m, 64);
    if ((t & 63) == 0) ws[t >> 6] = v;
    __syncthreads();
    if (t == 0) tsum[blockIdx.x] = ws[0] + ws[1] + ws[2] + ws[3];
}

__global__ __launch_bounds__(1024) void hscan_kernel(
    const int* __restrict__ tsum, int* __restrict__ tbase, int* __restrict__ rowptr_last)
{
    __shared__ int buf[1024];
    const int t = threadIdx.x;
    const int v = (t < NSB2) ? tsum[t] : 0;
    buf[t] = v;
    __syncthreads();
    for (int off = 1; off < 1024; off <<= 1) {
        const int add = (t >= off) ? buf[t - off] : 0;
        __syncthreads();
        buf[t] += add;
        __syncthreads();
    }
    if (t < NSB2) tbase[t] = buf[t] - v;
    if (t == 0) rowptr_last[0] = N_EDGES;
}

__global__ __launch_bounds__(256) void hwb_kernel(
    const int* __restrict__ hist_g, const int* __restrict__ tbase,
    int* __restrict__ base_g)
{
    __shared__ int buf[256];
    const int t = threadIdx.x;
    const int idx = blockIdx.x * 256 + t;
    const int v = (idx < HM) ? hist_g[idx] : 0;
    buf[t] = v;
    __syncthreads();
    for (int off = 1; off < 256; off <<= 1) {
        const int add = (t >= off) ? buf[t - off] : 0;
        __syncthreads();
        buf[t] += add;
        __syncthreads();
    }
    if (idx < HM) base_g[idx] = buf[t] - v + tbase[blockIdx.x];
}

__global__ __launch_bounds__(256) void bscatter_kernel(
    const int* __restrict__ esrc, const int* __restrict__ edst,
    const int* __restrict__ base_g, unsigned int* __restrict__ packed)
{
    __shared__ int rcur[NBUK];
    const int t = threadIdx.x;
    const int b = blockIdx.x;
    for (int i = t; i < NBUK; i += 256) rcur[i] = base_g[i * NFB + b];
    __syncthreads();
    const int e0 = b * EPB;
    #pragma unroll 5
    for (int k = 0; k < EPB / 256; ++k) {
        const int i = e0 + k * 256 + t;
        const int src = esrc[i];
        const int dst = edst[i];
        const int p = atomicAdd(&rcur[dst >> 6], 1);
        packed[p] = ((unsigned int)dst << 16) | (unsigned int)src;
    }
}

__global__ __launch_bounds__(256) void bfine_kernel(
    const unsigned int* __restrict__ packed, const int* __restrict__ base_g,
    int* __restrict__ rowptr, unsigned short* __restrict__ csr_src)
{
    __shared__ int cnt64[64], cur64[64], sexcl[64];
    const int t = threadIdx.x;
    const int j = blockIdx.x;
    const int s0 = base_g[j * NFB];
    const int s1 = (j + 1 < NBUK) ? base_g[(j + 1) * NFB] : N_EDGES;
    if (t < 64) cnt64[t] = 0;
    __syncthreads();
    for (int i = s0 + t; i < s1; i += 256)
        atomicAdd(&cnt64[(packed[i] >> 16) & 63], 1);
    __syncthreads();
    if (t == 0) {
        int run = 0;
        #pragma unroll
        for (int l = 0; l < 64; ++l) { sexcl[l] = run; run += cnt64[l]; }
    }
    __syncthreads();
    if (t < 64) {
        cur64[t] = 0;
        const int n = (j << 6) + t;
        if (n < N_NODES) rowptr[n] = s0 + sexcl[t];
    }
    __syncthreads();
    for (int i = s0 + t; i < s1; i += 256) {
        const unsigned int pk = packed[i];
        const int dl = (pk >> 16) & 63;
        const int p = atomicAdd(&cur64[dl], 1);
        csr_src[s0 + sexcl[dl] + p] = (unsigned short)(pk & 0xffff);
    }
}

// ---------------- gather aggregation: out[n] = bias + sum_{e in row n} h[src] -
// h rows are BF16 (256 B for D=128): halves the random-row HBM/L3 traffic
// that bound this kernel (R12: 345 MB FETCH, 3.5 TB/s, 43% peak).
// fp32 accumulation, same 4-chain order as before.
template <int D, bool RELU>
__global__ __launch_bounds__(D) void gather_kernel(
    const unsigned short* __restrict__ h, const int* __restrict__ rowptr,
    const unsigned short* __restrict__ csr_src, const float* __restrict__ bias,
    float* __restrict__ out)
{
    const int n = blockIdx.x, t = threadIdx.x;
    const int s0 = rowptr[n], s1 = rowptr[n + 1];
    float a0 = bias[t], a1 = 0.f, a2 = 0.f, a3 = 0.f;
    int e = s0;
    for (; e + 3 < s1; e += 4) {
        const int i0 = csr_src[e + 0];
        const int i1 = csr_src[e + 1];
        const int i2 = csr_src[e + 2];
        const int i3 = csr_src[e + 3];
        a0 += bf2f(h[(size_t)i0 * D + t]);
        a1 += bf2f(h[(size_t)i1 * D + t]);
        a2 += bf2f(h[(size_t)i2 * D + t]);
        a3 += bf2f(h[(size_t)i3 * D + t]);
    }
    for (; e < s1; ++e) a0 += bf2f(h[(size_t)csr_src[e] * D + t]);
    float acc = (a0 + a1) + (a2 + a3);
    if (RELU) acc = fmaxf(acc, 0.f);
    out[(size_t)n * D + t] = acc;
}

// ---------------- finalize: reduce 2*NGBLK gate partials + write tail --------
__global__ __launch_bounds__(1024) void finalize_kernel(
    const float* __restrict__ gpart, float* __restrict__ out_tail)
{
    __shared__ float wsum[16];
    const int t = threadIdx.x;
    float s = 0.f;
    for (int i = t; i < 2 * NGBLK; i += 1024) s += gpart[i];
    #pragma unroll
    for (int m = 32; m >= 1; m >>= 1) s += __shfl_xor(s, m, 64);
    if ((t & 63) == 0) wsum[t >> 6] = s;
    __syncthreads();
    if (t == 0) {
        float tot = 0.f;
        #pragma unroll
        for (int w = 0; w < 16; ++w) tot += wsum[w];
        out_tail[0] = tot * (0.5f / (float)N_NODES);
        out_tail[1] = 1.0f;
    }
}

extern "C" void kernel_launch(void* const* d_in, const int* in_sizes, int n_in,
                              void* d_out, int out_size, void* d_ws, size_t ws_size,
                              hipStream_t stream)
{
    const float* x     = (const float*)d_in[0];
    const int*   edge  = (const int*)d_in[1];
    const float* Wg1   = (const float*)d_in[2];
    const float* bg1   = (const float*)d_in[3];
    const float* We1   = (const float*)d_in[4];
    const float* be1   = (const float*)d_in[5];
    const float* b1    = (const float*)d_in[6];
    const float* Wg2   = (const float*)d_in[7];
    const float* bg2   = (const float*)d_in[8];
    const float* We2   = (const float*)d_in[9];
    const float* be2   = (const float*)d_in[10];
    const float* b2    = (const float*)d_in[11];
    const float* Wlast = (const float*)d_in[12];
    const float* blast = (const float*)d_in[13];
    float* out = (float*)d_out;

    const int* esrc = edge;
    const int* edst = edge + N_EDGES;

    char* ws = (char*)d_ws;
    size_t off = 0;
    float* gpart = (float*)(ws + off); off += (size_t)2 * NGBLK * 4 + 252; off &= ~(size_t)255;
    float* A = (float*)(ws + off); off += (size_t)N_NODES * 128 * 4;
    float* B = (float*)(ws + off); off += (size_t)N_NODES * 128 * 4;
    int* rowptr = (int*)(ws + off); off += (size_t)(N_NODES + 1) * 4 + 252; off &= ~(size_t)255;
    int* eidx = (int*)(ws + off); off += (size_t)N_NODES * 4 + 252; off &= ~(size_t)255;
    unsigned short* csr_src = (unsigned short*)(ws + off); off += (size_t)N_EDGES * 2 + 252; off &= ~(size_t)255;
    int* elist = (int*)(ws + off); off += (size_t)N_NODES * 4 + 252; off &= ~(size_t)255;
    int* meta = (int*)(ws + off); off += 256;
    int* ecnt = meta;          // 16
    int* eoff = meta + 16;     // 17
    int* ecur = meta + 33;     // 16

    // bf16 intermediate h (per-expert / last outputs), lives in A's slab
    unsigned short* Abf = (unsigned short*)A;     // 12.8 MB (128-dim) / 6.4 MB (64-dim)

    // CSR temporaries alias A and B (both dead until layer 1 compute):
    unsigned int* packed = (unsigned int*)A;      // 6.4 MB <= 25.6 MB
    int* hist_g = (int*)B;                        // HM ints
    int* base_g = hist_g + HM;                    // HM ints
    int* tsum   = base_g + HM;                    // NSB2 ints
    int* tbase  = tsum + NSB2;                    // NSB2 ints (total ~1.6 MB)

    // ---- CSR build (no global atomics) ----
    bhist_kernel<<<NFB, 256, 0, stream>>>(edst, hist_g);
    hpre_kernel<<<NSB2, 256, 0, stream>>>(hist_g, tsum);
    hscan_kernel<<<1, 1024, 0, stream>>>(tsum, tbase, rowptr + N_NODES);
    hwb_kernel<<<NSB2, 256, 0, stream>>>(hist_g, tbase, base_g);
    bscatter_kernel<<<NFB, 256, 0, stream>>>(esrc, edst, base_g, packed);
    bfine_kernel<<<NBUK, 256, 0, stream>>>(packed, base_g, rowptr, csr_src);

    const int nbk = (N_NODES + 255) / 256;

    // ---- layer 1 ----
    gate_kernel<<<NGBLK, 256, 0, stream>>>(x, Wg1, bg1, eidx, gpart);
    hipMemsetAsync(ecnt, 0, 64, stream);
    hist16_kernel<<<nbk, 256, 0, stream>>>(eidx, ecnt);
    scan16_kernel<<<1, 64, 0, stream>>>(ecnt, eoff, ecur);
    scatter16_kernel<<<nbk, 256, 0, stream>>>(eidx, ecur, elist);
    expert_gemm_kernel<<<dim3(N_EXPERT, NYB), 256, 0, stream>>>(x, We1, be1, eoff, elist, Abf);
    gather_kernel<128, true><<<N_NODES, 128, 0, stream>>>(Abf, rowptr, csr_src, b1, B);

    // ---- layer 2 ----
    gate_kernel<<<NGBLK, 256, 0, stream>>>(B, Wg2, bg2, eidx, gpart + NGBLK);
    hipMemsetAsync(ecnt, 0, 64, stream);
    hist16_kernel<<<nbk, 256, 0, stream>>>(eidx, ecnt);
    scan16_kernel<<<1, 64, 0, stream>>>(ecnt, eoff, ecur);
    scatter16_kernel<<<nbk, 256, 0, stream>>>(eidx, ecur, elist);
    expert_gemm_kernel<<<dim3(N_EXPERT, NYB), 256, 0, stream>>>(B, We2, be2, eoff, elist, Abf);
    gather_kernel<128, true><<<N_NODES, 128, 0, stream>>>(Abf, rowptr, csr_src, b2, B);

    // ---- layer 3 (plain GCNConv) ----
    last_kernel<<<N_NODES / NB, 64, 0, stream>>>(B, Wlast, Abf);
    gather_kernel<64, false><<<N_NODES, 64, 0, stream>>>(Abf, rowptr, csr_src, blast, out);

    finalize_kernel<<<1, 1024, 0, stream>>>(gpart, out + (size_t)N_NODES * 64);
}